// Round 6
// baseline (550.012 us; speedup 1.0000x reference)
//
#include <hip/hip_runtime.h>

#define NN 50000
#define NE 400000
#define NG 64
#define D 256
#define DOUT 16

typedef __attribute__((ext_vector_type(8))) short bf16x8;
typedef __attribute__((ext_vector_type(4))) float f32x4;

__device__ __forceinline__ short f2bf(float x) {
    union { float f; unsigned u; } v; v.f = x;
    unsigned r = v.u + 0x7fffu + ((v.u >> 16) & 1u);   // RNE
    return (short)(r >> 16);
}
__device__ __forceinline__ float bf2f(short h) {
    union { float f; unsigned u; } v;
    v.u = ((unsigned)(unsigned short)h) << 16;
    return v.f;
}

// ---------------- setup: degree, dinv, CSR by dst ----------------

__global__ void k_zero_cnt(int* cnt, int n) {
    int i = blockIdx.x * blockDim.x + threadIdx.x;
    if (i < n) cnt[i] = 0;
}

__global__ void k_zero_f(float* p, int n) {
    int i = blockIdx.x * blockDim.x + threadIdx.x;
    if (i < n) p[i] = 0.f;
}

__global__ void k_count(const int* __restrict__ eidx, int* __restrict__ cnt, int E) {
    int e = blockIdx.x * blockDim.x + threadIdx.x;
    if (e < E) atomicAdd(&cnt[eidx[E + e]], 1);
}

__global__ void k_dinv(const int* __restrict__ cnt, float* __restrict__ dinv, int n) {
    int i = blockIdx.x * blockDim.x + threadIdx.x;
    if (i < n) dinv[i] = rsqrtf((float)(cnt[i] + 1));  // +1 self-loop; always > 0
}

// exclusive scan of cnt[n] -> row_ptr[n], 1024 elems/block
__global__ void k_scan1(const int* __restrict__ cnt, int* __restrict__ excl,
                        int* __restrict__ bsums, int n) {
    __shared__ int sh[256];
    int tid = threadIdx.x;
    int base = blockIdx.x * 1024;
    int v[4]; int tsum = 0;
    for (int j = 0; j < 4; ++j) {
        int i = base + tid * 4 + j;
        v[j] = (i < n) ? cnt[i] : 0;
        tsum += v[j];
    }
    sh[tid] = tsum; __syncthreads();
    for (int d = 1; d < 256; d <<= 1) {
        int t = (tid >= d) ? sh[tid - d] : 0;
        __syncthreads();
        sh[tid] += t;
        __syncthreads();
    }
    int run = sh[tid] - tsum;  // exclusive offset within block
    for (int j = 0; j < 4; ++j) {
        int i = base + tid * 4 + j;
        if (i < n) excl[i] = run;
        run += v[j];
    }
    if (tid == 255) bsums[blockIdx.x] = sh[255];
}

__global__ void k_scan2(int* bsums, int nb) {
    __shared__ int sh[64];
    int tid = threadIdx.x;
    int v = (tid < nb) ? bsums[tid] : 0;
    sh[tid] = v; __syncthreads();
    for (int d = 1; d < 64; d <<= 1) {
        int t = (tid >= d) ? sh[tid - d] : 0;
        __syncthreads();
        sh[tid] += t;
        __syncthreads();
    }
    if (tid < nb) bsums[tid] = sh[tid] - v;  // exclusive
}

__global__ void k_scan3(int* __restrict__ row_ptr, const int* __restrict__ bsums,
                        int* __restrict__ cursor, int n, int E) {
    int i = blockIdx.x * blockDim.x + threadIdx.x;
    if (i < n) {
        int v = row_ptr[i] + bsums[i >> 10];
        row_ptr[i] = v;
        cursor[i] = v;
    }
    if (i == 0) row_ptr[n] = E;
}

__global__ void k_fill(const int* __restrict__ eidx, int* __restrict__ cursor,
                       int* __restrict__ col_src, int E) {
    int e = blockIdx.x * blockDim.x + threadIdx.x;
    if (e < E) {
        int d = eidx[E + e];
        int pos = atomicAdd(&cursor[d], 1);
        col_src[pos] = eidx[e];
    }
}

// per-graph inverse counts from sorted batch (64 threads, binary search)
__global__ void k_gcnt(const int* __restrict__ batch, float* __restrict__ inv_cnt, int n) {
    int g = threadIdx.x;
    if (g >= NG) return;
    int lo = 0, hi = n;
    while (lo < hi) { int mid = (lo + hi) >> 1; if (batch[mid] < g) lo = mid + 1; else hi = mid; }
    int start = lo;
    hi = n;
    while (lo < hi) { int mid = (lo + hi) >> 1; if (batch[mid] < g + 1) lo = mid + 1; else hi = mid; }
    inv_cnt[g] = 1.f / fmaxf((float)(lo - start), 1.f);
}

// ---------------- W -> W^T split into bf16 hi/lo: Wt[n][k] ----------------

__global__ void k_wsplit(const float* __restrict__ W, short* __restrict__ Whi,
                         short* __restrict__ Wlo) {
    int idx = blockIdx.x * 256 + threadIdx.x;  // idx = n*256 + k
    int n = idx >> 8, k = idx & 255;
    float x = W[k * 256 + n];
    short h = f2bf(x);
    Whi[idx] = h;
    Wlo[idx] = f2bf(x - bf2f(h));
}

// ---------------- x (fp32) -> hi/lo bf16, float4-vectorized ----------------

__global__ void k_xsplit(const float* __restrict__ x, unsigned short* __restrict__ hi,
                         unsigned short* __restrict__ lo, int total4) {
    int i = blockIdx.x * blockDim.x + threadIdx.x;
    if (i >= total4) return;
    float4 v = ((const float4*)x)[i];
    ushort4 h, l;
    h.x = (unsigned short)f2bf(v.x); l.x = (unsigned short)f2bf(v.x - bf2f(h.x));
    h.y = (unsigned short)f2bf(v.y); l.y = (unsigned short)f2bf(v.y - bf2f(h.y));
    h.z = (unsigned short)f2bf(v.z); l.z = (unsigned short)f2bf(v.z - bf2f(h.z));
    h.w = (unsigned short)f2bf(v.w); l.w = (unsigned short)f2bf(v.w - bf2f(h.w));
    ((ushort4*)hi)[i] = h;
    ((ushort4*)lo)[i] = l;
}

// ---------------- register-direct MFMA GEMM (no LDS, no barriers) ----------
// A hi/lo bf16 [M][256]; Wt hi/lo bf16 [256 n][256 k]. 128x128 tile, 4 waves
// of 64x64. Fragments are 16 B contiguous global loads (A: L1-shared by 2
// waves; W: 256 KB, L2-resident across all blocks).
// A*B ~= Ahi*Bhi + Alo*Bhi + Ahi*Blo  (fp32 MFMA accumulate)

__global__ __launch_bounds__(256) void k_gemm_mfma(
        const unsigned short* __restrict__ Ahi, const unsigned short* __restrict__ Alo,
        const short* __restrict__ Whi, const short* __restrict__ Wlo,
        const float* __restrict__ dinv, unsigned short* __restrict__ C, int M) {
    const int tid = threadIdx.x;
    const int bm = blockIdx.x * 128;
    const int bn = blockIdx.y * 128;

    const int lane = tid & 63;
    const int w    = tid >> 6;
    const int wm   = w & 1;        // wave row (0-1)
    const int wn   = w >> 1;       // wave col (0-1)
    const int lm   = lane & 15;
    const int quad = lane >> 4;

    f32x4 acc[4][4];
    #pragma unroll
    for (int i = 0; i < 4; ++i)
        #pragma unroll
        for (int j = 0; j < 4; ++j)
            acc[i][j] = (f32x4){0.f, 0.f, 0.f, 0.f};

    // per-lane row bases (clamped A rows never stored; clamp avoids OOB reads)
    size_t aoff[4], boff[4];
    #pragma unroll
    for (int i = 0; i < 4; ++i) {
        int ar = bm + wm * 64 + i * 16 + lm;
        if (ar >= M) ar = M - 1;
        aoff[i] = ((size_t)ar << 8) + quad * 8;
        int br = bn + wn * 64 + i * 16 + lm;
        boff[i] = ((size_t)br << 8) + quad * 8;
    }

    for (int k0 = 0; k0 < D; k0 += 32) {
        bf16x8 Ah[4], Al[4], Bh[4], Bl[4];
        #pragma unroll
        for (int i = 0; i < 4; ++i) {
            Ah[i] = *(const bf16x8*)(Ahi + aoff[i] + k0);
            Al[i] = *(const bf16x8*)(Alo + aoff[i] + k0);
            Bh[i] = *(const bf16x8*)(Whi + boff[i] + k0);
            Bl[i] = *(const bf16x8*)(Wlo + boff[i] + k0);
        }
        #pragma unroll
        for (int mi = 0; mi < 4; ++mi)
            #pragma unroll
            for (int ni = 0; ni < 4; ++ni) {
                acc[mi][ni] = __builtin_amdgcn_mfma_f32_16x16x32_bf16(Ah[mi], Bh[ni], acc[mi][ni], 0, 0, 0);
                acc[mi][ni] = __builtin_amdgcn_mfma_f32_16x16x32_bf16(Al[mi], Bh[ni], acc[mi][ni], 0, 0, 0);
                acc[mi][ni] = __builtin_amdgcn_mfma_f32_16x16x32_bf16(Ah[mi], Bl[ni], acc[mi][ni], 0, 0, 0);
            }
    }

    // epilogue: C[row][col] = bf16(acc * dinv[row])
    #pragma unroll
    for (int mi = 0; mi < 4; ++mi) {
        int rbase = bm + wm * 64 + mi * 16 + quad * 4;
        #pragma unroll
        for (int r = 0; r < 4; ++r) {
            int grow = rbase + r;
            if (grow < M) {
                float s = dinv[grow];
                #pragma unroll
                for (int ni = 0; ni < 4; ++ni) {
                    int col = bn + wn * 64 + ni * 16 + lm;
                    C[(size_t)grow * D + col] = (unsigned short)f2bf(acc[mi][ni][r] * s);
                }
            }
        }
    }
}

// ---------------- aggregation: out = relu(dinv*(h'[d] + sum h'[src]) + b) ----
// h' is bf16; one wave per node; lane i owns dims 4i..4i+3. Output written as
// split hi/lo bf16 (next GEMM's A operand). Index loads coalesced 64-wide;
// gathers issued 8 deep.

__global__ __launch_bounds__(256) void k_agg(
        const unsigned short* __restrict__ h, const float* __restrict__ dinv,
        const int* __restrict__ row_ptr, const int* __restrict__ col_src,
        const float* __restrict__ bias,
        unsigned short* __restrict__ ohi, unsigned short* __restrict__ olo, int n) {
    int node = blockIdx.x * 4 + (threadIdx.x >> 6);
    if (node >= n) return;
    int lane = threadIdx.x & 63;
    float di = dinv[node];
    ushort4 sv = ((const ushort4*)(h + (size_t)node * D))[lane];  // self-loop
    float4 acc = make_float4(bf2f(sv.x), bf2f(sv.y), bf2f(sv.z), bf2f(sv.w));
    int beg = row_ptr[node], end = row_ptr[node + 1];

    for (int c = beg; c < end; c += 64) {
        int cnt = min(64, end - c);                       // wave-uniform
        int myidx = (lane < cnt) ? col_src[c + lane] : 0; // one coalesced index load
        int e = 0;
        while (e < cnt) {
            int k = min(8, cnt - e);                      // wave-uniform
            ushort4 v[8];
            #pragma unroll
            for (int j = 0; j < 8; ++j) {
                if (j < k) {
                    int s = __shfl(myidx, e + j);         // broadcast, register-only
                    v[j] = ((const ushort4*)(h + (size_t)s * D))[lane];
                }
            }
            #pragma unroll
            for (int j = 0; j < 8; ++j) {
                if (j < k) {
                    acc.x += bf2f(v[j].x); acc.y += bf2f(v[j].y);
                    acc.z += bf2f(v[j].z); acc.w += bf2f(v[j].w);
                }
            }
            e += k;
        }
    }

    float4 b = ((const float4*)bias)[lane];
    float4 r;
    r.x = fmaxf(acc.x * di + b.x, 0.f);
    r.y = fmaxf(acc.y * di + b.y, 0.f);
    r.z = fmaxf(acc.z * di + b.z, 0.f);
    r.w = fmaxf(acc.w * di + b.w, 0.f);
    ushort4 hh, ll;
    hh.x = (unsigned short)f2bf(r.x); ll.x = (unsigned short)f2bf(r.x - bf2f(hh.x));
    hh.y = (unsigned short)f2bf(r.y); ll.y = (unsigned short)f2bf(r.y - bf2f(hh.y));
    hh.z = (unsigned short)f2bf(r.z); ll.z = (unsigned short)f2bf(r.z - bf2f(hh.z));
    hh.w = (unsigned short)f2bf(r.w); ll.w = (unsigned short)f2bf(r.w - bf2f(hh.w));
    ((ushort4*)(ohi + (size_t)node * D))[lane] = hh;
    ((ushort4*)(olo + (size_t)node * D))[lane] = ll;
}

// ---------------- mean pool, stage 1: chunked sums + atomic flush ----------------
// reads hi+lo (reconstructs ~fp32); 64 contiguous nodes per block.

__global__ __launch_bounds__(256) void k_pool_sum(
        const unsigned short* __restrict__ hi, const unsigned short* __restrict__ lo,
        const int* __restrict__ batch, float* __restrict__ pooled, int n) {
    int beg = blockIdx.x * 64;
    if (beg >= n) return;
    int end = min(beg + 64, n);
    int t = threadIdx.x;  // dim t
    float acc = 0.f;
    int cur = batch[beg];
    for (int i = beg; i < end; ++i) {
        int g = batch[i];
        if (g != cur) {
            atomicAdd(&pooled[cur * D + t], acc);
            acc = 0.f;
            cur = g;
        }
        size_t o = (size_t)i * D + t;
        acc += bf2f(hi[o]) + bf2f(lo[o]);
    }
    atomicAdd(&pooled[cur * D + t], acc);
}

// ---------------- final FC: out[g,o] = bfc[o] + inv_cnt[g] * (pooled_sum[g] . W[:,o]) ----

__global__ void k_fc(const float* __restrict__ pooled, const float* __restrict__ inv_cnt,
                     const float* __restrict__ W, const float* __restrict__ b,
                     float* __restrict__ out) {
    int t = blockIdx.x * blockDim.x + threadIdx.x;
    if (t >= NG * DOUT) return;
    int g = t >> 4, o = t & 15;
    float acc = 0.f;
    for (int k = 0; k < D; ++k) acc += pooled[g * D + k] * W[k * DOUT + o];
    out[t] = acc * inv_cnt[g] + b[o];
}

// ---------------- launch ----------------

extern "C" void kernel_launch(void* const* d_in, const int* in_sizes, int n_in,
                              void* d_out, int out_size, void* d_ws, size_t ws_size,
                              hipStream_t stream) {
    const float* x    = (const float*)d_in[0];
    const int*   eidx = (const int*)d_in[1];
    const int*   batch= (const int*)d_in[2];
    const float* W1   = (const float*)d_in[3];
    const float* b1   = (const float*)d_in[4];
    const float* W2   = (const float*)d_in[5];
    const float* b2   = (const float*)d_in[6];
    const float* W3   = (const float*)d_in[7];
    const float* b3   = (const float*)d_in[8];
    const float* Wfc  = (const float*)d_in[9];
    const float* bfc  = (const float*)d_in[10];
    float* out = (float*)d_out;

    const int n = in_sizes[0] / D;      // 50000
    const int E = in_sizes[1] / 2;      // 400000

    // workspace layout (256B aligned slabs)
    char* p = (char*)d_ws;
    auto take = [&](size_t bytes) -> void* {
        void* q = (void*)p;
        p += (bytes + 255) & ~(size_t)255;
        return q;
    };
    int*   cnt     = (int*)take((size_t)n * 4);
    int*   row_ptr = (int*)take((size_t)(n + 1) * 4);
    int*   cursor  = (int*)take((size_t)n * 4);
    int*   col_src = (int*)take((size_t)E * 4);
    int*   bsums   = (int*)take(256 * 4);
    float* dinv    = (float*)take((size_t)n * 4);
    float* inv_cnt = (float*)take((size_t)NG * 4);
    short* w1hi    = (short*)take((size_t)D * D * 2);
    short* w1lo    = (short*)take((size_t)D * D * 2);
    short* w2hi    = (short*)take((size_t)D * D * 2);
    short* w2lo    = (short*)take((size_t)D * D * 2);
    short* w3hi    = (short*)take((size_t)D * D * 2);
    short* w3lo    = (short*)take((size_t)D * D * 2);
    unsigned short* hbuf = (unsigned short*)take((size_t)n * D * 2);  // bf16 h'
    unsigned short* ahi  = (unsigned short*)take((size_t)n * D * 2);  // A hi (xsplit/agg out)
    unsigned short* alo  = (unsigned short*)take((size_t)n * D * 2);  // A lo
    float* pooled  = (float*)take((size_t)NG * D * 4);

    int tb = 256;
    int gn = (n + tb - 1) / tb;
    int ge = (E + tb - 1) / tb;
    int nb = (n + 1023) / 1024;   // 49 scan blocks

    k_zero_cnt<<<gn, tb, 0, stream>>>(cnt, n);
    k_zero_f<<<(NG * D + 255) / 256, 256, 0, stream>>>(pooled, NG * D);
    k_gcnt<<<1, 64, 0, stream>>>(batch, inv_cnt, n);
    k_wsplit<<<D, 256, 0, stream>>>(W1, w1hi, w1lo);
    k_wsplit<<<D, 256, 0, stream>>>(W2, w2hi, w2lo);
    k_wsplit<<<D, 256, 0, stream>>>(W3, w3hi, w3lo);
    k_xsplit<<<(n * D / 4 + 255) / 256, 256, 0, stream>>>(x, ahi, alo, n * D / 4);
    k_count<<<ge, tb, 0, stream>>>(eidx, cnt, E);
    k_dinv<<<gn, tb, 0, stream>>>(cnt, dinv, n);
    k_scan1<<<nb, 256, 0, stream>>>(cnt, row_ptr, bsums, n);
    k_scan2<<<1, 64, 0, stream>>>(bsums, nb);
    k_scan3<<<gn, tb, 0, stream>>>(row_ptr, bsums, cursor, n, E);
    k_fill<<<ge, tb, 0, stream>>>(eidx, cursor, col_src, E);

    dim3 ggrid((n + 127) / 128, 2);
    int agrid = (n + 3) / 4;

    // ahi/alo double duty: xsplit output for layer 1, then agg output for 2/3
    k_gemm_mfma<<<ggrid, 256, 0, stream>>>(ahi, alo, w1hi, w1lo, dinv, hbuf, n);
    k_agg<<<agrid, 256, 0, stream>>>(hbuf, dinv, row_ptr, col_src, b1, ahi, alo, n);

    k_gemm_mfma<<<ggrid, 256, 0, stream>>>(ahi, alo, w2hi, w2lo, dinv, hbuf, n);
    k_agg<<<agrid, 256, 0, stream>>>(hbuf, dinv, row_ptr, col_src, b2, ahi, alo, n);

    k_gemm_mfma<<<ggrid, 256, 0, stream>>>(ahi, alo, w3hi, w3lo, dinv, hbuf, n);
    k_agg<<<agrid, 256, 0, stream>>>(hbuf, dinv, row_ptr, col_src, b3, ahi, alo, n);

    k_pool_sum<<<(n + 63) / 64, 256, 0, stream>>>(ahi, alo, batch, pooled, n);
    k_fc<<<4, 256, 0, stream>>>(pooled, inv_cnt, Wfc, bfc, out);
}

// Round 7
// 458.298 us; speedup vs baseline: 1.2001x; 1.2001x over previous
//
#include <hip/hip_runtime.h>

#define NN 50000
#define NE 400000
#define NG 64
#define D 256
#define DOUT 16

typedef __attribute__((ext_vector_type(8))) short bf16x8;
typedef __attribute__((ext_vector_type(4))) float f32x4;

__device__ __forceinline__ short f2bf(float x) {
    union { float f; unsigned u; } v; v.f = x;
    unsigned r = v.u + 0x7fffu + ((v.u >> 16) & 1u);   // RNE
    return (short)(r >> 16);
}
__device__ __forceinline__ float bf2f(short h) {
    union { float f; unsigned u; } v;
    v.u = ((unsigned)(unsigned short)h) << 16;
    return v.f;
}

// async global->LDS 16B copy (dest = wave-uniform base + lane*16)
__device__ __forceinline__ void async_cp16(void* lds, const void* g) {
    __builtin_amdgcn_global_load_lds(
        (const __attribute__((address_space(1))) unsigned int*)g,
        (__attribute__((address_space(3))) unsigned int*)lds, 16, 0, 0);
}

// ---------------- setup: degree, dinv, CSR by dst ----------------

__global__ void k_zero_cnt(int* cnt, int n) {
    int i = blockIdx.x * blockDim.x + threadIdx.x;
    if (i < n) cnt[i] = 0;
}

__global__ void k_zero_f(float* p, int n) {
    int i = blockIdx.x * blockDim.x + threadIdx.x;
    if (i < n) p[i] = 0.f;
}

__global__ void k_count(const int* __restrict__ eidx, int* __restrict__ cnt, int E) {
    int e = blockIdx.x * blockDim.x + threadIdx.x;
    if (e < E) atomicAdd(&cnt[eidx[E + e]], 1);
}

__global__ void k_dinv(const int* __restrict__ cnt, float* __restrict__ dinv, int n) {
    int i = blockIdx.x * blockDim.x + threadIdx.x;
    if (i < n) dinv[i] = rsqrtf((float)(cnt[i] + 1));  // +1 self-loop; always > 0
}

// exclusive scan of cnt[n] -> row_ptr[n], 1024 elems/block
__global__ void k_scan1(const int* __restrict__ cnt, int* __restrict__ excl,
                        int* __restrict__ bsums, int n) {
    __shared__ int sh[256];
    int tid = threadIdx.x;
    int base = blockIdx.x * 1024;
    int v[4]; int tsum = 0;
    for (int j = 0; j < 4; ++j) {
        int i = base + tid * 4 + j;
        v[j] = (i < n) ? cnt[i] : 0;
        tsum += v[j];
    }
    sh[tid] = tsum; __syncthreads();
    for (int d = 1; d < 256; d <<= 1) {
        int t = (tid >= d) ? sh[tid - d] : 0;
        __syncthreads();
        sh[tid] += t;
        __syncthreads();
    }
    int run = sh[tid] - tsum;  // exclusive offset within block
    for (int j = 0; j < 4; ++j) {
        int i = base + tid * 4 + j;
        if (i < n) excl[i] = run;
        run += v[j];
    }
    if (tid == 255) bsums[blockIdx.x] = sh[255];
}

__global__ void k_scan2(int* bsums, int nb) {
    __shared__ int sh[64];
    int tid = threadIdx.x;
    int v = (tid < nb) ? bsums[tid] : 0;
    sh[tid] = v; __syncthreads();
    for (int d = 1; d < 64; d <<= 1) {
        int t = (tid >= d) ? sh[tid - d] : 0;
        __syncthreads();
        sh[tid] += t;
        __syncthreads();
    }
    if (tid < nb) bsums[tid] = sh[tid] - v;  // exclusive
}

__global__ void k_scan3(int* __restrict__ row_ptr, const int* __restrict__ bsums,
                        int* __restrict__ cursor, int n, int E) {
    int i = blockIdx.x * blockDim.x + threadIdx.x;
    if (i < n) {
        int v = row_ptr[i] + bsums[i >> 10];
        row_ptr[i] = v;
        cursor[i] = v;
    }
    if (i == 0) row_ptr[n] = E;
}

__global__ void k_fill(const int* __restrict__ eidx, int* __restrict__ cursor,
                       int* __restrict__ col_src, int E) {
    int e = blockIdx.x * blockDim.x + threadIdx.x;
    if (e < E) {
        int d = eidx[E + e];
        int pos = atomicAdd(&cursor[d], 1);
        col_src[pos] = eidx[e];
    }
}

// per-graph inverse counts from sorted batch (64 threads, binary search)
__global__ void k_gcnt(const int* __restrict__ batch, float* __restrict__ inv_cnt, int n) {
    int g = threadIdx.x;
    if (g >= NG) return;
    int lo = 0, hi = n;
    while (lo < hi) { int mid = (lo + hi) >> 1; if (batch[mid] < g) lo = mid + 1; else hi = mid; }
    int start = lo;
    hi = n;
    while (lo < hi) { int mid = (lo + hi) >> 1; if (batch[mid] < g + 1) lo = mid + 1; else hi = mid; }
    inv_cnt[g] = 1.f / fmaxf((float)(lo - start), 1.f);
}

// ---------------- W -> W^T split into bf16 hi/lo: Wt[n][k] ----------------

__global__ void k_wsplit(const float* __restrict__ W, short* __restrict__ Whi,
                         short* __restrict__ Wlo) {
    int idx = blockIdx.x * 256 + threadIdx.x;  // idx = n*256 + k
    int n = idx >> 8, k = idx & 255;
    float x = W[k * 256 + n];
    short h = f2bf(x);
    Whi[idx] = h;
    Wlo[idx] = f2bf(x - bf2f(h));
}

// ---------------- x (fp32) -> hi/lo bf16, float4-vectorized ----------------

__global__ void k_xsplit(const float* __restrict__ x, unsigned short* __restrict__ hi,
                         unsigned short* __restrict__ lo, int total4) {
    int i = blockIdx.x * blockDim.x + threadIdx.x;
    if (i >= total4) return;
    float4 v = ((const float4*)x)[i];
    ushort4 h, l;
    h.x = (unsigned short)f2bf(v.x); l.x = (unsigned short)f2bf(v.x - bf2f(h.x));
    h.y = (unsigned short)f2bf(v.y); l.y = (unsigned short)f2bf(v.y - bf2f(h.y));
    h.z = (unsigned short)f2bf(v.z); l.z = (unsigned short)f2bf(v.z - bf2f(h.z));
    h.w = (unsigned short)f2bf(v.w); l.w = (unsigned short)f2bf(v.w - bf2f(h.w));
    ((ushort4*)hi)[i] = h;
    ((ushort4*)lo)[i] = l;
}

// ---------------- MFMA GEMM: LDS-staged via global_load_lds, pre-split A ----
// A hi/lo bf16 [M][256]; Wt hi/lo bf16 [256 n][256 k]. 128x128 tile, 4 waves
// of 64x64, BK=32. LDS slot (row r, quad col c) holds k-quad q = c ^ ((r>>1)&3)
// (XOR swizzle folded into the *global* source address, since global_load_lds
// destinations are lane-ordered and can't be padded). Fragment ds_read_b128:
// 16 rows x 64B stride -> 2-way bank alias only (free).
// A*B ~= Ahi*Bhi + Alo*Bhi + Ahi*Blo  (fp32 MFMA accumulate)

__global__ __launch_bounds__(256) void k_gemm_mfma(
        const unsigned short* __restrict__ Ahi, const unsigned short* __restrict__ Alo,
        const short* __restrict__ Whi, const short* __restrict__ Wlo,
        const float* __restrict__ dinv, unsigned short* __restrict__ C, int M) {
    __shared__ short Ah_s[4096];   // 128 rows x 32 k (8 KB), swizzled
    __shared__ short Al_s[4096];
    __shared__ short Bh_s[4096];
    __shared__ short Bl_s[4096];

    const int tid = threadIdx.x;
    const int bm = blockIdx.x * 128;
    const int bn = blockIdx.y * 128;

    const int lane = tid & 63;
    const int w    = tid >> 6;
    const int wm   = w & 1;        // wave row (0-1)
    const int wn   = w >> 1;       // wave col (0-1)
    const int lm   = lane & 15;
    const int quad = lane >> 4;

    // ---- staging source addresses (per thread, two 64-row issues) ----
    // issue j: row r = j*64 + (tid>>2); col c = tid&3; holds quad q = c^((r>>1)&3)
    const int srow = tid >> 2, c = tid & 3;
    const int r0 = srow, r1 = 64 + srow;
    const int q0 = c ^ ((r0 >> 1) & 3);
    const int q1 = c ^ ((r1 >> 1) & 3);
    int ga0 = bm + r0; if (ga0 >= M) ga0 = M - 1;   // clamp: dup rows never stored
    int ga1 = bm + r1; if (ga1 >= M) ga1 = M - 1;
    const unsigned short* pah0 = Ahi + ((size_t)ga0 << 8) + q0 * 8;
    const unsigned short* pah1 = Ahi + ((size_t)ga1 << 8) + q1 * 8;
    const unsigned short* pal0 = Alo + ((size_t)ga0 << 8) + q0 * 8;
    const unsigned short* pal1 = Alo + ((size_t)ga1 << 8) + q1 * 8;
    const short* pbh0 = Whi + ((size_t)(bn + r0) << 8) + q0 * 8;
    const short* pbh1 = Whi + ((size_t)(bn + r1) << 8) + q1 * 8;
    const short* pbl0 = Wlo + ((size_t)(bn + r0) << 8) + q0 * 8;
    const short* pbl1 = Wlo + ((size_t)(bn + r1) << 8) + q1 * 8;

    // wave-uniform LDS dest bases (shorts): issue j region j*2048, wave w at +w*512
    const int st0 = w * 512;
    const int st1 = 2048 + w * 512;

    // ---- fragment LDS offsets (k0-invariant) ----
    int oa[4], ob[4];
    #pragma unroll
    for (int i = 0; i < 4; ++i) {
        int ra = wm * 64 + i * 16 + lm;
        oa[i] = ra * 32 + ((quad ^ ((ra >> 1) & 3)) * 8);
        int rb = wn * 64 + i * 16 + lm;
        ob[i] = rb * 32 + ((quad ^ ((rb >> 1) & 3)) * 8);
    }

    f32x4 acc[4][4];
    #pragma unroll
    for (int i = 0; i < 4; ++i)
        #pragma unroll
        for (int j = 0; j < 4; ++j)
            acc[i][j] = (f32x4){0.f, 0.f, 0.f, 0.f};

    for (int k0 = 0; k0 < D; k0 += 32) {
        async_cp16(&Ah_s[st0], pah0 + k0);
        async_cp16(&Ah_s[st1], pah1 + k0);
        async_cp16(&Al_s[st0], pal0 + k0);
        async_cp16(&Al_s[st1], pal1 + k0);
        async_cp16(&Bh_s[st0], pbh0 + k0);
        async_cp16(&Bh_s[st1], pbh1 + k0);
        async_cp16(&Bl_s[st0], pbl0 + k0);
        async_cp16(&Bl_s[st1], pbl1 + k0);
        __syncthreads();

        bf16x8 Ah[4], Al[4], Bh[4], Bl[4];
        #pragma unroll
        for (int i = 0; i < 4; ++i) {
            Ah[i] = *(const bf16x8*)&Ah_s[oa[i]];
            Al[i] = *(const bf16x8*)&Al_s[oa[i]];
            Bh[i] = *(const bf16x8*)&Bh_s[ob[i]];
            Bl[i] = *(const bf16x8*)&Bl_s[ob[i]];
        }
        #pragma unroll
        for (int mi = 0; mi < 4; ++mi)
            #pragma unroll
            for (int ni = 0; ni < 4; ++ni) {
                acc[mi][ni] = __builtin_amdgcn_mfma_f32_16x16x32_bf16(Ah[mi], Bh[ni], acc[mi][ni], 0, 0, 0);
                acc[mi][ni] = __builtin_amdgcn_mfma_f32_16x16x32_bf16(Al[mi], Bh[ni], acc[mi][ni], 0, 0, 0);
                acc[mi][ni] = __builtin_amdgcn_mfma_f32_16x16x32_bf16(Ah[mi], Bl[ni], acc[mi][ni], 0, 0, 0);
            }
        __syncthreads();
    }

    // epilogue: C[row][col] = bf16(acc * dinv[row])
    #pragma unroll
    for (int mi = 0; mi < 4; ++mi) {
        int rbase = bm + wm * 64 + mi * 16 + quad * 4;
        #pragma unroll
        for (int r = 0; r < 4; ++r) {
            int grow = rbase + r;
            if (grow < M) {
                float s = dinv[grow];
                #pragma unroll
                for (int ni = 0; ni < 4; ++ni) {
                    int col = bn + wn * 64 + ni * 16 + lm;
                    C[(size_t)grow * D + col] = (unsigned short)f2bf(acc[mi][ni][r] * s);
                }
            }
        }
    }
}

// ---------------- aggregation: out = relu(dinv*(h'[d] + sum h'[src]) + b) ----
// h' is bf16; one wave per node; lane i owns dims 4i..4i+3. Output written as
// split hi/lo bf16 (next GEMM's A operand). Index loads coalesced 64-wide;
// gathers issued 8 deep.

__global__ __launch_bounds__(256) void k_agg(
        const unsigned short* __restrict__ h, const float* __restrict__ dinv,
        const int* __restrict__ row_ptr, const int* __restrict__ col_src,
        const float* __restrict__ bias,
        unsigned short* __restrict__ ohi, unsigned short* __restrict__ olo, int n) {
    int node = blockIdx.x * 4 + (threadIdx.x >> 6);
    if (node >= n) return;
    int lane = threadIdx.x & 63;
    float di = dinv[node];
    ushort4 sv = ((const ushort4*)(h + (size_t)node * D))[lane];  // self-loop
    float4 acc = make_float4(bf2f(sv.x), bf2f(sv.y), bf2f(sv.z), bf2f(sv.w));
    int beg = row_ptr[node], end = row_ptr[node + 1];

    for (int c = beg; c < end; c += 64) {
        int cnt = min(64, end - c);                       // wave-uniform
        int myidx = (lane < cnt) ? col_src[c + lane] : 0; // one coalesced index load
        int e = 0;
        while (e < cnt) {
            int k = min(8, cnt - e);                      // wave-uniform
            ushort4 v[8];
            #pragma unroll
            for (int j = 0; j < 8; ++j) {
                if (j < k) {
                    int s = __shfl(myidx, e + j);         // broadcast, register-only
                    v[j] = ((const ushort4*)(h + (size_t)s * D))[lane];
                }
            }
            #pragma unroll
            for (int j = 0; j < 8; ++j) {
                if (j < k) {
                    acc.x += bf2f(v[j].x); acc.y += bf2f(v[j].y);
                    acc.z += bf2f(v[j].z); acc.w += bf2f(v[j].w);
                }
            }
            e += k;
        }
    }

    float4 b = ((const float4*)bias)[lane];
    float4 r;
    r.x = fmaxf(acc.x * di + b.x, 0.f);
    r.y = fmaxf(acc.y * di + b.y, 0.f);
    r.z = fmaxf(acc.z * di + b.z, 0.f);
    r.w = fmaxf(acc.w * di + b.w, 0.f);
    ushort4 hh, ll;
    hh.x = (unsigned short)f2bf(r.x); ll.x = (unsigned short)f2bf(r.x - bf2f(hh.x));
    hh.y = (unsigned short)f2bf(r.y); ll.y = (unsigned short)f2bf(r.y - bf2f(hh.y));
    hh.z = (unsigned short)f2bf(r.z); ll.z = (unsigned short)f2bf(r.z - bf2f(hh.z));
    hh.w = (unsigned short)f2bf(r.w); ll.w = (unsigned short)f2bf(r.w - bf2f(hh.w));
    ((ushort4*)(ohi + (size_t)node * D))[lane] = hh;
    ((ushort4*)(olo + (size_t)node * D))[lane] = ll;
}

// ---------------- mean pool, stage 1: chunked sums + atomic flush ----------------
// reads hi+lo (reconstructs ~fp32); 64 contiguous nodes per block.

__global__ __launch_bounds__(256) void k_pool_sum(
        const unsigned short* __restrict__ hi, const unsigned short* __restrict__ lo,
        const int* __restrict__ batch, float* __restrict__ pooled, int n) {
    int beg = blockIdx.x * 64;
    if (beg >= n) return;
    int end = min(beg + 64, n);
    int t = threadIdx.x;  // dim t
    float acc = 0.f;
    int cur = batch[beg];
    for (int i = beg; i < end; ++i) {
        int g = batch[i];
        if (g != cur) {
            atomicAdd(&pooled[cur * D + t], acc);
            acc = 0.f;
            cur = g;
        }
        size_t o = (size_t)i * D + t;
        acc += bf2f(hi[o]) + bf2f(lo[o]);
    }
    atomicAdd(&pooled[cur * D + t], acc);
}

// ---------------- final FC: out[g,o] = bfc[o] + inv_cnt[g] * (pooled_sum[g] . W[:,o]) ----

__global__ void k_fc(const float* __restrict__ pooled, const float* __restrict__ inv_cnt,
                     const float* __restrict__ W, const float* __restrict__ b,
                     float* __restrict__ out) {
    int t = blockIdx.x * blockDim.x + threadIdx.x;
    if (t >= NG * DOUT) return;
    int g = t >> 4, o = t & 15;
    float acc = 0.f;
    for (int k = 0; k < D; ++k) acc += pooled[g * D + k] * W[k * DOUT + o];
    out[t] = acc * inv_cnt[g] + b[o];
}

// ---------------- launch ----------------

extern "C" void kernel_launch(void* const* d_in, const int* in_sizes, int n_in,
                              void* d_out, int out_size, void* d_ws, size_t ws_size,
                              hipStream_t stream) {
    const float* x    = (const float*)d_in[0];
    const int*   eidx = (const int*)d_in[1];
    const int*   batch= (const int*)d_in[2];
    const float* W1   = (const float*)d_in[3];
    const float* b1   = (const float*)d_in[4];
    const float* W2   = (const float*)d_in[5];
    const float* b2   = (const float*)d_in[6];
    const float* W3   = (const float*)d_in[7];
    const float* b3   = (const float*)d_in[8];
    const float* Wfc  = (const float*)d_in[9];
    const float* bfc  = (const float*)d_in[10];
    float* out = (float*)d_out;

    const int n = in_sizes[0] / D;      // 50000
    const int E = in_sizes[1] / 2;      // 400000

    // workspace layout (256B aligned slabs)
    char* p = (char*)d_ws;
    auto take = [&](size_t bytes) -> void* {
        void* q = (void*)p;
        p += (bytes + 255) & ~(size_t)255;
        return q;
    };
    int*   cnt     = (int*)take((size_t)n * 4);
    int*   row_ptr = (int*)take((size_t)(n + 1) * 4);
    int*   cursor  = (int*)take((size_t)n * 4);
    int*   col_src = (int*)take((size_t)E * 4);
    int*   bsums   = (int*)take(256 * 4);
    float* dinv    = (float*)take((size_t)n * 4);
    float* inv_cnt = (float*)take((size_t)NG * 4);
    short* w1hi    = (short*)take((size_t)D * D * 2);
    short* w1lo    = (short*)take((size_t)D * D * 2);
    short* w2hi    = (short*)take((size_t)D * D * 2);
    short* w2lo    = (short*)take((size_t)D * D * 2);
    short* w3hi    = (short*)take((size_t)D * D * 2);
    short* w3lo    = (short*)take((size_t)D * D * 2);
    unsigned short* hbuf = (unsigned short*)take((size_t)n * D * 2);  // bf16 h'
    unsigned short* ahi  = (unsigned short*)take((size_t)n * D * 2);  // A hi (xsplit/agg out)
    unsigned short* alo  = (unsigned short*)take((size_t)n * D * 2);  // A lo
    float* pooled  = (float*)take((size_t)NG * D * 4);

    int tb = 256;
    int gn = (n + tb - 1) / tb;
    int ge = (E + tb - 1) / tb;
    int nb = (n + 1023) / 1024;   // 49 scan blocks

    k_zero_cnt<<<gn, tb, 0, stream>>>(cnt, n);
    k_zero_f<<<(NG * D + 255) / 256, 256, 0, stream>>>(pooled, NG * D);
    k_gcnt<<<1, 64, 0, stream>>>(batch, inv_cnt, n);
    k_wsplit<<<D, 256, 0, stream>>>(W1, w1hi, w1lo);
    k_wsplit<<<D, 256, 0, stream>>>(W2, w2hi, w2lo);
    k_wsplit<<<D, 256, 0, stream>>>(W3, w3hi, w3lo);
    k_xsplit<<<(n * D / 4 + 255) / 256, 256, 0, stream>>>(x, ahi, alo, n * D / 4);
    k_count<<<ge, tb, 0, stream>>>(eidx, cnt, E);
    k_dinv<<<gn, tb, 0, stream>>>(cnt, dinv, n);
    k_scan1<<<nb, 256, 0, stream>>>(cnt, row_ptr, bsums, n);
    k_scan2<<<1, 64, 0, stream>>>(bsums, nb);
    k_scan3<<<gn, tb, 0, stream>>>(row_ptr, bsums, cursor, n, E);
    k_fill<<<ge, tb, 0, stream>>>(eidx, cursor, col_src, E);

    dim3 ggrid((n + 127) / 128, 2);
    int agrid = (n + 3) / 4;

    // ahi/alo double duty: xsplit output for layer 1, then agg output for 2/3
    k_gemm_mfma<<<ggrid, 256, 0, stream>>>(ahi, alo, w1hi, w1lo, dinv, hbuf, n);
    k_agg<<<agrid, 256, 0, stream>>>(hbuf, dinv, row_ptr, col_src, b1, ahi, alo, n);

    k_gemm_mfma<<<ggrid, 256, 0, stream>>>(ahi, alo, w2hi, w2lo, dinv, hbuf, n);
    k_agg<<<agrid, 256, 0, stream>>>(hbuf, dinv, row_ptr, col_src, b2, ahi, alo, n);

    k_gemm_mfma<<<ggrid, 256, 0, stream>>>(ahi, alo, w3hi, w3lo, dinv, hbuf, n);
    k_agg<<<agrid, 256, 0, stream>>>(hbuf, dinv, row_ptr, col_src, b3, ahi, alo, n);

    k_pool_sum<<<(n + 63) / 64, 256, 0, stream>>>(ahi, alo, batch, pooled, n);
    k_fc<<<4, 256, 0, stream>>>(pooled, inv_cnt, Wfc, bfc, out);
}

// Round 8
// 410.057 us; speedup vs baseline: 1.3413x; 1.1176x over previous
//
#include <hip/hip_runtime.h>

#define NN 50000
#define NE 400000
#define NG 64
#define D 256
#define DOUT 16

typedef __attribute__((ext_vector_type(8))) short bf16x8;
typedef __attribute__((ext_vector_type(4))) float f32x4;

__device__ __forceinline__ short f2bf(float x) {
    union { float f; unsigned u; } v; v.f = x;
    unsigned r = v.u + 0x7fffu + ((v.u >> 16) & 1u);   // RNE
    return (short)(r >> 16);
}
__device__ __forceinline__ float bf2f(short h) {
    union { float f; unsigned u; } v;
    v.u = ((unsigned)(unsigned short)h) << 16;
    return v.f;
}

// async global->LDS 16B copy (dest = wave-uniform base + lane*16)
__device__ __forceinline__ void async_cp16(void* lds, const void* g) {
    __builtin_amdgcn_global_load_lds(
        (const __attribute__((address_space(1))) unsigned int*)g,
        (__attribute__((address_space(3))) unsigned int*)lds, 16, 0, 0);
}

// ---------------- init: zero cnt + zero pooled + per-graph inv counts ------

__global__ void k_init(int* __restrict__ cnt, float* __restrict__ pooled,
                       const int* __restrict__ batch, float* __restrict__ inv_cnt,
                       int n) {
    int i = blockIdx.x * 256 + threadIdx.x;
    if (i < n) cnt[i] = 0;
    if (i < NG * D) pooled[i] = 0.f;
    if (blockIdx.x == 0 && threadIdx.x < NG) {
        int g = threadIdx.x;
        int lo = 0, hi = n;
        while (lo < hi) { int mid = (lo + hi) >> 1; if (batch[mid] < g) lo = mid + 1; else hi = mid; }
        int start = lo;
        hi = n;
        while (lo < hi) { int mid = (lo + hi) >> 1; if (batch[mid] < g + 1) lo = mid + 1; else hi = mid; }
        inv_cnt[g] = 1.f / fmaxf((float)(lo - start), 1.f);
    }
}

__global__ void k_count(const int* __restrict__ eidx, int* __restrict__ cnt, int E) {
    int e = blockIdx.x * blockDim.x + threadIdx.x;
    if (e < E) atomicAdd(&cnt[eidx[E + e]], 1);
}

// exclusive scan of cnt[n] -> row_ptr[n] (+ dinv from final counts), 1024 elems/block
__global__ void k_scan1(const int* __restrict__ cnt, int* __restrict__ excl,
                        int* __restrict__ bsums, float* __restrict__ dinv, int n) {
    __shared__ int sh[256];
    int tid = threadIdx.x;
    int base = blockIdx.x * 1024;
    int v[4]; int tsum = 0;
    for (int j = 0; j < 4; ++j) {
        int i = base + tid * 4 + j;
        v[j] = (i < n) ? cnt[i] : 0;
        if (i < n) dinv[i] = rsqrtf((float)(v[j] + 1));  // +1 self-loop
        tsum += v[j];
    }
    sh[tid] = tsum; __syncthreads();
    for (int d = 1; d < 256; d <<= 1) {
        int t = (tid >= d) ? sh[tid - d] : 0;
        __syncthreads();
        sh[tid] += t;
        __syncthreads();
    }
    int run = sh[tid] - tsum;  // exclusive offset within block
    for (int j = 0; j < 4; ++j) {
        int i = base + tid * 4 + j;
        if (i < n) excl[i] = run;
        run += v[j];
    }
    if (tid == 255) bsums[blockIdx.x] = sh[255];
}

__global__ void k_scan2(int* bsums, int nb) {
    __shared__ int sh[64];
    int tid = threadIdx.x;
    int v = (tid < nb) ? bsums[tid] : 0;
    sh[tid] = v; __syncthreads();
    for (int d = 1; d < 64; d <<= 1) {
        int t = (tid >= d) ? sh[tid - d] : 0;
        __syncthreads();
        sh[tid] += t;
        __syncthreads();
    }
    if (tid < nb) bsums[tid] = sh[tid] - v;  // exclusive
}

__global__ void k_scan3(int* __restrict__ row_ptr, const int* __restrict__ bsums,
                        int* __restrict__ cursor, int n, int E) {
    int i = blockIdx.x * blockDim.x + threadIdx.x;
    if (i < n) {
        int v = row_ptr[i] + bsums[i >> 10];
        row_ptr[i] = v;
        cursor[i] = v;
    }
    if (i == 0) row_ptr[n] = E;
}

__global__ void k_fill(const int* __restrict__ eidx, int* __restrict__ cursor,
                       int* __restrict__ col_src, int E) {
    int e = blockIdx.x * blockDim.x + threadIdx.x;
    if (e < E) {
        int d = eidx[E + e];
        int pos = atomicAdd(&cursor[d], 1);
        col_src[pos] = eidx[e];
    }
}

// ---------------- split: x -> bf16 (hi only) + 3x W -> W^T hi/lo ----------
// grid = xblocks + 3*256; first xblocks blocks convert x (float4-wide),
// remaining do the W transpose-splits.

__global__ void k_split(const float* __restrict__ x, unsigned short* __restrict__ ahi,
                        int total4, int xblocks,
                        const float* __restrict__ W1, short* __restrict__ w1hi, short* __restrict__ w1lo,
                        const float* __restrict__ W2, short* __restrict__ w2hi, short* __restrict__ w2lo,
                        const float* __restrict__ W3, short* __restrict__ w3hi, short* __restrict__ w3lo) {
    if (blockIdx.x < (unsigned)xblocks) {
        int i = blockIdx.x * 256 + threadIdx.x;
        if (i >= total4) return;
        float4 v = ((const float4*)x)[i];
        ushort4 h;
        h.x = (unsigned short)f2bf(v.x);
        h.y = (unsigned short)f2bf(v.y);
        h.z = (unsigned short)f2bf(v.z);
        h.w = (unsigned short)f2bf(v.w);
        ((ushort4*)ahi)[i] = h;
    } else {
        int wb = blockIdx.x - xblocks;
        int which = wb >> 8;               // 0..2
        int idx = (wb & 255) * 256 + threadIdx.x;   // idx = n*256 + k
        int nn = idx >> 8, k = idx & 255;
        const float* W = (which == 0) ? W1 : (which == 1) ? W2 : W3;
        short* Whi = (which == 0) ? w1hi : (which == 1) ? w2hi : w3hi;
        short* Wlo = (which == 0) ? w1lo : (which == 1) ? w2lo : w3lo;
        float xv = W[k * 256 + nn];
        short h = f2bf(xv);
        Whi[idx] = h;
        Wlo[idx] = f2bf(xv - bf2f(h));
    }
}

// ---------------- MFMA GEMM: LDS-staged via global_load_lds ----------------
// A bf16 [M][256] (hi only); Wt hi/lo bf16 [256 n][256 k]. 128x128 tile,
// 4 waves of 64x64, BK=32. LDS slot (row r, quad col c) holds k-quad
// q = c ^ ((r>>1)&3) (XOR swizzle folded into the *global* source address).
// A*B ~= Ah*Bh + Ah*Bl  (W full precision; A bf16 — per-node error pools out)

__global__ __launch_bounds__(256) void k_gemm_mfma(
        const unsigned short* __restrict__ A,
        const short* __restrict__ Whi, const short* __restrict__ Wlo,
        const float* __restrict__ dinv, unsigned short* __restrict__ C, int M) {
    __shared__ short Ah_s[4096];   // 128 rows x 32 k (8 KB), swizzled
    __shared__ short Bh_s[4096];
    __shared__ short Bl_s[4096];

    const int tid = threadIdx.x;
    const int bm = blockIdx.x * 128;
    const int bn = blockIdx.y * 128;

    const int lane = tid & 63;
    const int w    = tid >> 6;
    const int wm   = w & 1;        // wave row (0-1)
    const int wn   = w >> 1;       // wave col (0-1)
    const int lm   = lane & 15;
    const int quad = lane >> 4;

    // staging source addresses (per thread, two 64-row issues)
    const int srow = tid >> 2, c = tid & 3;
    const int r0 = srow, r1 = 64 + srow;
    const int q0 = c ^ ((r0 >> 1) & 3);
    const int q1 = c ^ ((r1 >> 1) & 3);
    int ga0 = bm + r0; if (ga0 >= M) ga0 = M - 1;   // clamp: dup rows never stored
    int ga1 = bm + r1; if (ga1 >= M) ga1 = M - 1;
    const unsigned short* pah0 = A + ((size_t)ga0 << 8) + q0 * 8;
    const unsigned short* pah1 = A + ((size_t)ga1 << 8) + q1 * 8;
    const short* pbh0 = Whi + ((size_t)(bn + r0) << 8) + q0 * 8;
    const short* pbh1 = Whi + ((size_t)(bn + r1) << 8) + q1 * 8;
    const short* pbl0 = Wlo + ((size_t)(bn + r0) << 8) + q0 * 8;
    const short* pbl1 = Wlo + ((size_t)(bn + r1) << 8) + q1 * 8;

    // wave-uniform LDS dest bases (shorts)
    const int st0 = w * 512;
    const int st1 = 2048 + w * 512;

    // fragment LDS offsets (k0-invariant)
    int oa[4], ob[4];
    #pragma unroll
    for (int i = 0; i < 4; ++i) {
        int ra = wm * 64 + i * 16 + lm;
        oa[i] = ra * 32 + ((quad ^ ((ra >> 1) & 3)) * 8);
        int rb = wn * 64 + i * 16 + lm;
        ob[i] = rb * 32 + ((quad ^ ((rb >> 1) & 3)) * 8);
    }

    f32x4 acc[4][4];
    #pragma unroll
    for (int i = 0; i < 4; ++i)
        #pragma unroll
        for (int j = 0; j < 4; ++j)
            acc[i][j] = (f32x4){0.f, 0.f, 0.f, 0.f};

    for (int k0 = 0; k0 < D; k0 += 32) {
        async_cp16(&Ah_s[st0], pah0 + k0);
        async_cp16(&Ah_s[st1], pah1 + k0);
        async_cp16(&Bh_s[st0], pbh0 + k0);
        async_cp16(&Bh_s[st1], pbh1 + k0);
        async_cp16(&Bl_s[st0], pbl0 + k0);
        async_cp16(&Bl_s[st1], pbl1 + k0);
        __syncthreads();

        bf16x8 Ah[4], Bh[4], Bl[4];
        #pragma unroll
        for (int i = 0; i < 4; ++i) {
            Ah[i] = *(const bf16x8*)&Ah_s[oa[i]];
            Bh[i] = *(const bf16x8*)&Bh_s[ob[i]];
            Bl[i] = *(const bf16x8*)&Bl_s[ob[i]];
        }
        #pragma unroll
        for (int mi = 0; mi < 4; ++mi)
            #pragma unroll
            for (int ni = 0; ni < 4; ++ni) {
                acc[mi][ni] = __builtin_amdgcn_mfma_f32_16x16x32_bf16(Ah[mi], Bh[ni], acc[mi][ni], 0, 0, 0);
                acc[mi][ni] = __builtin_amdgcn_mfma_f32_16x16x32_bf16(Ah[mi], Bl[ni], acc[mi][ni], 0, 0, 0);
            }
        __syncthreads();
    }

    // epilogue: C[row][col] = bf16(acc * dinv[row])
    #pragma unroll
    for (int mi = 0; mi < 4; ++mi) {
        int rbase = bm + wm * 64 + mi * 16 + quad * 4;
        #pragma unroll
        for (int r = 0; r < 4; ++r) {
            int grow = rbase + r;
            if (grow < M) {
                float s = dinv[grow];
                #pragma unroll
                for (int ni = 0; ni < 4; ++ni) {
                    int col = bn + wn * 64 + ni * 16 + lm;
                    C[(size_t)grow * D + col] = (unsigned short)f2bf(acc[mi][ni][r] * s);
                }
            }
        }
    }
}

// ---------------- aggregation: out = relu(dinv*(h'[d] + sum h'[src]) + b) ----
// h' is bf16; TWO nodes per wave (CSR-adjacent), gathers issued 8+8 deep =
// 16 outstanding misses/wave. lane i owns dims 4i..4i+3. Output bf16 (hi only).

__global__ __launch_bounds__(256) void k_agg(
        const unsigned short* __restrict__ h, const float* __restrict__ dinv,
        const int* __restrict__ row_ptr, const int* __restrict__ col_src,
        const float* __restrict__ bias,
        unsigned short* __restrict__ ohi, int n) {
    int w = threadIdx.x >> 6, lane = threadIdx.x & 63;
    int n0 = blockIdx.x * 8 + w * 2;
    if (n0 >= n) return;
    int n1 = n0 + 1;
    bool has1 = n1 < n;

    float di0 = dinv[n0];
    float di1 = has1 ? dinv[n1] : 0.f;
    ushort4 s0 = ((const ushort4*)(h + (size_t)n0 * D))[lane];
    float4 a0 = make_float4(bf2f(s0.x), bf2f(s0.y), bf2f(s0.z), bf2f(s0.w));
    float4 a1 = make_float4(0.f, 0.f, 0.f, 0.f);
    if (has1) {
        ushort4 s1 = ((const ushort4*)(h + (size_t)n1 * D))[lane];
        a1 = make_float4(bf2f(s1.x), bf2f(s1.y), bf2f(s1.z), bf2f(s1.w));
    }

    int c0 = row_ptr[n0], e0 = row_ptr[n0 + 1];
    int c1 = e0, e1 = has1 ? row_ptr[n1 + 1] : e0;   // CSR-contiguous

    while (c0 < e0 || c1 < e1) {
        int cnt0 = min(64, e0 - c0); if (cnt0 < 0) cnt0 = 0;
        int cnt1 = min(64, e1 - c1); if (cnt1 < 0) cnt1 = 0;
        int i0 = (lane < cnt0) ? col_src[c0 + lane] : 0;
        int i1 = (lane < cnt1) ? col_src[c1 + lane] : 0;
        int m = max(cnt0, cnt1);
        for (int e = 0; e < m; e += 8) {
            int k0 = cnt0 - e;                        // wave-uniform
            int k1 = cnt1 - e;
            ushort4 u0[8], u1[8];
            #pragma unroll
            for (int j = 0; j < 8; ++j)
                if (j < k0) {
                    int s = __shfl(i0, e + j);
                    u0[j] = ((const ushort4*)(h + (size_t)s * D))[lane];
                }
            #pragma unroll
            for (int j = 0; j < 8; ++j)
                if (j < k1) {
                    int s = __shfl(i1, e + j);
                    u1[j] = ((const ushort4*)(h + (size_t)s * D))[lane];
                }
            #pragma unroll
            for (int j = 0; j < 8; ++j)
                if (j < k0) {
                    a0.x += bf2f(u0[j].x); a0.y += bf2f(u0[j].y);
                    a0.z += bf2f(u0[j].z); a0.w += bf2f(u0[j].w);
                }
            #pragma unroll
            for (int j = 0; j < 8; ++j)
                if (j < k1) {
                    a1.x += bf2f(u1[j].x); a1.y += bf2f(u1[j].y);
                    a1.z += bf2f(u1[j].z); a1.w += bf2f(u1[j].w);
                }
        }
        c0 += cnt0; c1 += cnt1;
    }

    float4 b = ((const float4*)bias)[lane];
    ushort4 o0;
    o0.x = (unsigned short)f2bf(fmaxf(a0.x * di0 + b.x, 0.f));
    o0.y = (unsigned short)f2bf(fmaxf(a0.y * di0 + b.y, 0.f));
    o0.z = (unsigned short)f2bf(fmaxf(a0.z * di0 + b.z, 0.f));
    o0.w = (unsigned short)f2bf(fmaxf(a0.w * di0 + b.w, 0.f));
    ((ushort4*)(ohi + (size_t)n0 * D))[lane] = o0;
    if (has1) {
        ushort4 o1;
        o1.x = (unsigned short)f2bf(fmaxf(a1.x * di1 + b.x, 0.f));
        o1.y = (unsigned short)f2bf(fmaxf(a1.y * di1 + b.y, 0.f));
        o1.z = (unsigned short)f2bf(fmaxf(a1.z * di1 + b.z, 0.f));
        o1.w = (unsigned short)f2bf(fmaxf(a1.w * di1 + b.w, 0.f));
        ((ushort4*)(ohi + (size_t)n1 * D))[lane] = o1;
    }
}

// ---------------- mean pool, stage 1: chunked sums + atomic flush ----------------

__global__ __launch_bounds__(256) void k_pool_sum(
        const unsigned short* __restrict__ hi,
        const int* __restrict__ batch, float* __restrict__ pooled, int n) {
    int beg = blockIdx.x * 64;
    if (beg >= n) return;
    int end = min(beg + 64, n);
    int t = threadIdx.x;  // dim t
    float acc = 0.f;
    int cur = batch[beg];
    for (int i = beg; i < end; ++i) {
        int g = batch[i];
        if (g != cur) {
            atomicAdd(&pooled[cur * D + t], acc);
            acc = 0.f;
            cur = g;
        }
        acc += bf2f(hi[(size_t)i * D + t]);
    }
    atomicAdd(&pooled[cur * D + t], acc);
}

// ---------------- final FC ----------------

__global__ void k_fc(const float* __restrict__ pooled, const float* __restrict__ inv_cnt,
                     const float* __restrict__ W, const float* __restrict__ b,
                     float* __restrict__ out) {
    int t = blockIdx.x * blockDim.x + threadIdx.x;
    if (t >= NG * DOUT) return;
    int g = t >> 4, o = t & 15;
    float acc = 0.f;
    for (int k = 0; k < D; ++k) acc += pooled[g * D + k] * W[k * DOUT + o];
    out[t] = acc * inv_cnt[g] + b[o];
}

// ---------------- launch ----------------

extern "C" void kernel_launch(void* const* d_in, const int* in_sizes, int n_in,
                              void* d_out, int out_size, void* d_ws, size_t ws_size,
                              hipStream_t stream) {
    const float* x    = (const float*)d_in[0];
    const int*   eidx = (const int*)d_in[1];
    const int*   batch= (const int*)d_in[2];
    const float* W1   = (const float*)d_in[3];
    const float* b1   = (const float*)d_in[4];
    const float* W2   = (const float*)d_in[5];
    const float* b2   = (const float*)d_in[6];
    const float* W3   = (const float*)d_in[7];
    const float* b3   = (const float*)d_in[8];
    const float* Wfc  = (const float*)d_in[9];
    const float* bfc  = (const float*)d_in[10];
    float* out = (float*)d_out;

    const int n = in_sizes[0] / D;      // 50000
    const int E = in_sizes[1] / 2;      // 400000

    // workspace layout (256B aligned slabs)
    char* p = (char*)d_ws;
    auto take = [&](size_t bytes) -> void* {
        void* q = (void*)p;
        p += (bytes + 255) & ~(size_t)255;
        return q;
    };
    int*   cnt     = (int*)take((size_t)n * 4);
    int*   row_ptr = (int*)take((size_t)(n + 1) * 4);
    int*   cursor  = (int*)take((size_t)n * 4);
    int*   col_src = (int*)take((size_t)E * 4);
    int*   bsums   = (int*)take(256 * 4);
    float* dinv    = (float*)take((size_t)n * 4);
    float* inv_cnt = (float*)take((size_t)NG * 4);
    short* w1hi    = (short*)take((size_t)D * D * 2);
    short* w1lo    = (short*)take((size_t)D * D * 2);
    short* w2hi    = (short*)take((size_t)D * D * 2);
    short* w2lo    = (short*)take((size_t)D * D * 2);
    short* w3hi    = (short*)take((size_t)D * D * 2);
    short* w3lo    = (short*)take((size_t)D * D * 2);
    unsigned short* hbuf = (unsigned short*)take((size_t)n * D * 2);  // bf16 h'
    unsigned short* ahi  = (unsigned short*)take((size_t)n * D * 2);  // bf16 A
    float* pooled  = (float*)take((size_t)NG * D * 4);

    int tb = 256;
    int gn = (n + tb - 1) / tb;
    int ge = (E + tb - 1) / tb;
    int nb = (n + 1023) / 1024;   // 49 scan blocks
    int total4 = n * D / 4;
    int xblocks = (total4 + 255) / 256;

    k_init<<<gn, tb, 0, stream>>>(cnt, pooled, batch, inv_cnt, n);
    k_split<<<xblocks + 3 * 256, tb, 0, stream>>>(x, ahi, total4, xblocks,
                                                  W1, w1hi, w1lo, W2, w2hi, w2lo, W3, w3hi, w3lo);
    k_count<<<ge, tb, 0, stream>>>(eidx, cnt, E);
    k_scan1<<<nb, 256, 0, stream>>>(cnt, row_ptr, bsums, dinv, n);
    k_scan2<<<1, 64, 0, stream>>>(bsums, nb);
    k_scan3<<<gn, tb, 0, stream>>>(row_ptr, bsums, cursor, n, E);
    k_fill<<<ge, tb, 0, stream>>>(eidx, cursor, col_src, E);

    dim3 ggrid((n + 127) / 128, 2);
    int agrid = (n + 7) / 8;

    k_gemm_mfma<<<ggrid, 256, 0, stream>>>(ahi, w1hi, w1lo, dinv, hbuf, n);
    k_agg<<<agrid, 256, 0, stream>>>(hbuf, dinv, row_ptr, col_src, b1, ahi, n);

    k_gemm_mfma<<<ggrid, 256, 0, stream>>>(ahi, w2hi, w2lo, dinv, hbuf, n);
    k_agg<<<agrid, 256, 0, stream>>>(hbuf, dinv, row_ptr, col_src, b2, ahi, n);

    k_gemm_mfma<<<ggrid, 256, 0, stream>>>(ahi, w3hi, w3lo, dinv, hbuf, n);
    k_agg<<<agrid, 256, 0, stream>>>(hbuf, dinv, row_ptr, col_src, b3, ahi, n);

    k_pool_sum<<<(n + 63) / 64, 256, 0, stream>>>(ahi, batch, pooled, n);
    k_fc<<<4, 256, 0, stream>>>(pooled, inv_cnt, Wfc, bfc, out);
}

// Round 9
// 404.924 us; speedup vs baseline: 1.3583x; 1.0127x over previous
//
#include <hip/hip_runtime.h>

#define NN 50000
#define NE 400000
#define NG 64
#define D 256
#define DOUT 16

typedef __attribute__((ext_vector_type(8))) short bf16x8;
typedef __attribute__((ext_vector_type(4))) float f32x4;

__device__ __forceinline__ short f2bf(float x) {
    union { float f; unsigned u; } v; v.f = x;
    unsigned r = v.u + 0x7fffu + ((v.u >> 16) & 1u);   // RNE
    return (short)(r >> 16);
}
__device__ __forceinline__ float bf2f(short h) {
    union { float f; unsigned u; } v;
    v.u = ((unsigned)(unsigned short)h) << 16;
    return v.f;
}

// async global->LDS 16B copy (dest = wave-uniform base + lane*16)
__device__ __forceinline__ void async_cp16(void* lds, const void* g) {
    __builtin_amdgcn_global_load_lds(
        (const __attribute__((address_space(1))) unsigned int*)g,
        (__attribute__((address_space(3))) unsigned int*)lds, 16, 0, 0);
}

// ---------------- init: zero cnt + zero pooled + per-graph inv counts ------

__global__ void k_init(int* __restrict__ cnt, float* __restrict__ pooled,
                       const int* __restrict__ batch, float* __restrict__ inv_cnt,
                       int n) {
    int i = blockIdx.x * 256 + threadIdx.x;
    if (i < n) cnt[i] = 0;
    if (i < NG * D) pooled[i] = 0.f;
    if (blockIdx.x == 0 && threadIdx.x < NG) {
        int g = threadIdx.x;
        int lo = 0, hi = n;
        while (lo < hi) { int mid = (lo + hi) >> 1; if (batch[mid] < g) lo = mid + 1; else hi = mid; }
        int start = lo;
        hi = n;
        while (lo < hi) { int mid = (lo + hi) >> 1; if (batch[mid] < g + 1) lo = mid + 1; else hi = mid; }
        inv_cnt[g] = 1.f / fmaxf((float)(lo - start), 1.f);
    }
}

__global__ void k_count(const int* __restrict__ eidx, int* __restrict__ cnt, int E) {
    int e = blockIdx.x * blockDim.x + threadIdx.x;
    if (e < E) atomicAdd(&cnt[eidx[E + e]], 1);
}

// exclusive scan of cnt[n] -> row_ptr[n] (+ dinv from final counts), 1024 elems/block
__global__ void k_scan1(const int* __restrict__ cnt, int* __restrict__ excl,
                        int* __restrict__ bsums, float* __restrict__ dinv, int n) {
    __shared__ int sh[256];
    int tid = threadIdx.x;
    int base = blockIdx.x * 1024;
    int v[4]; int tsum = 0;
    for (int j = 0; j < 4; ++j) {
        int i = base + tid * 4 + j;
        v[j] = (i < n) ? cnt[i] : 0;
        if (i < n) dinv[i] = rsqrtf((float)(v[j] + 1));  // +1 self-loop
        tsum += v[j];
    }
    sh[tid] = tsum; __syncthreads();
    for (int d = 1; d < 256; d <<= 1) {
        int t = (tid >= d) ? sh[tid - d] : 0;
        __syncthreads();
        sh[tid] += t;
        __syncthreads();
    }
    int run = sh[tid] - tsum;  // exclusive offset within block
    for (int j = 0; j < 4; ++j) {
        int i = base + tid * 4 + j;
        if (i < n) excl[i] = run;
        run += v[j];
    }
    if (tid == 255) bsums[blockIdx.x] = sh[255];
}

__global__ void k_scan2(int* bsums, int nb) {
    __shared__ int sh[64];
    int tid = threadIdx.x;
    int v = (tid < nb) ? bsums[tid] : 0;
    sh[tid] = v; __syncthreads();
    for (int d = 1; d < 64; d <<= 1) {
        int t = (tid >= d) ? sh[tid - d] : 0;
        __syncthreads();
        sh[tid] += t;
        __syncthreads();
    }
    if (tid < nb) bsums[tid] = sh[tid] - v;  // exclusive
}

__global__ void k_scan3(int* __restrict__ row_ptr, const int* __restrict__ bsums,
                        int* __restrict__ cursor, int n, int E) {
    int i = blockIdx.x * blockDim.x + threadIdx.x;
    if (i < n) {
        int v = row_ptr[i] + bsums[i >> 10];
        row_ptr[i] = v;
        cursor[i] = v;
    }
    if (i == 0) row_ptr[n] = E;
}

__global__ void k_fill(const int* __restrict__ eidx, int* __restrict__ cursor,
                       int* __restrict__ col_src, int E) {
    int e = blockIdx.x * blockDim.x + threadIdx.x;
    if (e < E) {
        int d = eidx[E + e];
        int pos = atomicAdd(&cursor[d], 1);
        col_src[pos] = eidx[e];
    }
}

// ---------------- split: x -> bf16 (hi only) + 3x W -> W^T hi/lo ----------

__global__ void k_split(const float* __restrict__ x, unsigned short* __restrict__ ahi,
                        int total4, int xblocks,
                        const float* __restrict__ W1, short* __restrict__ w1hi, short* __restrict__ w1lo,
                        const float* __restrict__ W2, short* __restrict__ w2hi, short* __restrict__ w2lo,
                        const float* __restrict__ W3, short* __restrict__ w3hi, short* __restrict__ w3lo) {
    if (blockIdx.x < (unsigned)xblocks) {
        int i = blockIdx.x * 256 + threadIdx.x;
        if (i >= total4) return;
        float4 v = ((const float4*)x)[i];
        ushort4 h;
        h.x = (unsigned short)f2bf(v.x);
        h.y = (unsigned short)f2bf(v.y);
        h.z = (unsigned short)f2bf(v.z);
        h.w = (unsigned short)f2bf(v.w);
        ((ushort4*)ahi)[i] = h;
    } else {
        int wb = blockIdx.x - xblocks;
        int which = wb >> 8;               // 0..2
        int idx = (wb & 255) * 256 + threadIdx.x;   // idx = n*256 + k
        int nn = idx >> 8, k = idx & 255;
        const float* W = (which == 0) ? W1 : (which == 1) ? W2 : W3;
        short* Whi = (which == 0) ? w1hi : (which == 1) ? w2hi : w3hi;
        short* Wlo = (which == 0) ? w1lo : (which == 1) ? w2lo : w3lo;
        float xv = W[k * 256 + nn];
        short h = f2bf(xv);
        Whi[idx] = h;
        Wlo[idx] = f2bf(xv - bf2f(h));
    }
}

// ---------------- MFMA GEMM: 128x256 tile, LDS-staged via global_load_lds --
// A bf16 [M][256] (hi only); Wt hi/lo bf16 [256 n][256 k]. 4 waves of 64x128,
// BK=32, full N in one block (A fetched ONCE). XOR swizzle q = c ^ ((r>>1)&3)
// folded into global source address. A*B ~= Ah*Bh + Ah*Bl.

__global__ __launch_bounds__(256, 2) void k_gemm_mfma(
        const unsigned short* __restrict__ A,
        const short* __restrict__ Whi, const short* __restrict__ Wlo,
        const float* __restrict__ dinv, unsigned short* __restrict__ C, int M) {
    __shared__ short Ah_s[4096];   //  8 KB: 128 rows x 32 k, swizzled
    __shared__ short Bh_s[8192];   // 16 KB: 256 rows x 32 k
    __shared__ short Bl_s[8192];   // 16 KB

    const int tid = threadIdx.x;
    const int bm = blockIdx.x * 128;

    const int lane = tid & 63;
    const int w    = tid >> 6;
    const int wm   = w & 1;        // wave row half (0-1): 64 rows
    const int wn   = w >> 1;       // wave col half (0-1): 128 cols
    const int lm   = lane & 15;
    const int quad = lane >> 4;

    // staging source addressing: per issue of 64 rows, thread covers row tid>>2,
    // 16B chunk c = tid&3, holding swizzled quad q = c ^ ((srow>>1)&3)
    const int srow = tid >> 2, c = tid & 3;
    const int q = c ^ ((srow >> 1) & 3);          // j*64 doesn't affect (row>>1)&3
    int ga0 = bm + srow;        if (ga0 >= M) ga0 = M - 1;
    int ga1 = bm + 64 + srow;   if (ga1 >= M) ga1 = M - 1;
    const unsigned short* pa0 = A + ((size_t)ga0 << 8) + q * 8;
    const unsigned short* pa1 = A + ((size_t)ga1 << 8) + q * 8;
    const short* pbh[4]; const short* pbl[4];
    #pragma unroll
    for (int j = 0; j < 4; ++j) {
        pbh[j] = Whi + ((size_t)(j * 64 + srow) << 8) + q * 8;
        pbl[j] = Wlo + ((size_t)(j * 64 + srow) << 8) + q * 8;
    }

    const int stA0 = w * 512, stA1 = 2048 + w * 512;   // shorts
    int stB[4];
    #pragma unroll
    for (int j = 0; j < 4; ++j) stB[j] = j * 2048 + w * 512;

    // fragment LDS offsets (k0-invariant)
    int oa[4], ob[8];
    #pragma unroll
    for (int i = 0; i < 4; ++i) {
        int ra = wm * 64 + i * 16 + lm;
        oa[i] = ra * 32 + ((quad ^ ((ra >> 1) & 3)) * 8);
    }
    #pragma unroll
    for (int i = 0; i < 8; ++i) {
        int rb = wn * 128 + i * 16 + lm;
        ob[i] = rb * 32 + ((quad ^ ((rb >> 1) & 3)) * 8);
    }

    f32x4 acc[4][8];
    #pragma unroll
    for (int i = 0; i < 4; ++i)
        #pragma unroll
        for (int j = 0; j < 8; ++j)
            acc[i][j] = (f32x4){0.f, 0.f, 0.f, 0.f};

    for (int k0 = 0; k0 < D; k0 += 32) {
        async_cp16(&Ah_s[stA0], pa0 + k0);
        async_cp16(&Ah_s[stA1], pa1 + k0);
        #pragma unroll
        for (int j = 0; j < 4; ++j) {
            async_cp16(&Bh_s[stB[j]], pbh[j] + k0);
            async_cp16(&Bl_s[stB[j]], pbl[j] + k0);
        }
        __syncthreads();

        bf16x8 Ah[4], Bh[8], Bl[8];
        #pragma unroll
        for (int i = 0; i < 4; ++i) Ah[i] = *(const bf16x8*)&Ah_s[oa[i]];
        #pragma unroll
        for (int i = 0; i < 8; ++i) {
            Bh[i] = *(const bf16x8*)&Bh_s[ob[i]];
            Bl[i] = *(const bf16x8*)&Bl_s[ob[i]];
        }
        #pragma unroll
        for (int mi = 0; mi < 4; ++mi)
            #pragma unroll
            for (int ni = 0; ni < 8; ++ni) {
                acc[mi][ni] = __builtin_amdgcn_mfma_f32_16x16x32_bf16(Ah[mi], Bh[ni], acc[mi][ni], 0, 0, 0);
                acc[mi][ni] = __builtin_amdgcn_mfma_f32_16x16x32_bf16(Ah[mi], Bl[ni], acc[mi][ni], 0, 0, 0);
            }
        __syncthreads();
    }

    // epilogue: C[row][col] = bf16(acc * dinv[row])
    #pragma unroll
    for (int mi = 0; mi < 4; ++mi) {
        int rbase = bm + wm * 64 + mi * 16 + quad * 4;
        #pragma unroll
        for (int r = 0; r < 4; ++r) {
            int grow = rbase + r;
            if (grow < M) {
                float s = dinv[grow];
                #pragma unroll
                for (int ni = 0; ni < 8; ++ni) {
                    int col = wn * 128 + ni * 16 + lm;
                    C[(size_t)grow * D + col] = (unsigned short)f2bf(acc[mi][ni][r] * s);
                }
            }
        }
    }
}

// ---------------- agg core: r = relu(dinv*(h'[node] + sum h'[src]) + b) ----

__device__ __forceinline__ void agg_two(
        const unsigned short* __restrict__ h, const int* __restrict__ row_ptr,
        const int* __restrict__ col_src, int n0, int n1, bool has1, int lane,
        float4& a0, float4& a1) {
    ushort4 s0 = ((const ushort4*)(h + (size_t)n0 * D))[lane];
    a0 = make_float4(bf2f(s0.x), bf2f(s0.y), bf2f(s0.z), bf2f(s0.w));
    a1 = make_float4(0.f, 0.f, 0.f, 0.f);
    if (has1) {
        ushort4 s1 = ((const ushort4*)(h + (size_t)n1 * D))[lane];
        a1 = make_float4(bf2f(s1.x), bf2f(s1.y), bf2f(s1.z), bf2f(s1.w));
    }
    int c0 = row_ptr[n0], e0 = row_ptr[n0 + 1];
    int c1 = e0, e1 = has1 ? row_ptr[n1 + 1] : e0;   // CSR-contiguous

    while (c0 < e0 || c1 < e1) {
        int cnt0 = min(64, e0 - c0); if (cnt0 < 0) cnt0 = 0;
        int cnt1 = min(64, e1 - c1); if (cnt1 < 0) cnt1 = 0;
        int i0 = (lane < cnt0) ? col_src[c0 + lane] : 0;
        int i1 = (lane < cnt1) ? col_src[c1 + lane] : 0;
        int m = max(cnt0, cnt1);
        for (int e = 0; e < m; e += 8) {
            int k0 = cnt0 - e;                        // wave-uniform
            int k1 = cnt1 - e;
            ushort4 u0[8], u1[8];
            #pragma unroll
            for (int j = 0; j < 8; ++j)
                if (j < k0) {
                    int s = __shfl(i0, e + j);
                    u0[j] = ((const ushort4*)(h + (size_t)s * D))[lane];
                }
            #pragma unroll
            for (int j = 0; j < 8; ++j)
                if (j < k1) {
                    int s = __shfl(i1, e + j);
                    u1[j] = ((const ushort4*)(h + (size_t)s * D))[lane];
                }
            #pragma unroll
            for (int j = 0; j < 8; ++j)
                if (j < k0) {
                    a0.x += bf2f(u0[j].x); a0.y += bf2f(u0[j].y);
                    a0.z += bf2f(u0[j].z); a0.w += bf2f(u0[j].w);
                }
            #pragma unroll
            for (int j = 0; j < 8; ++j)
                if (j < k1) {
                    a1.x += bf2f(u1[j].x); a1.y += bf2f(u1[j].y);
                    a1.z += bf2f(u1[j].z); a1.w += bf2f(u1[j].w);
                }
        }
        c0 += cnt0; c1 += cnt1;
    }
}

// layers 1-2: write bf16 (next GEMM's A)
__global__ __launch_bounds__(256) void k_agg(
        const unsigned short* __restrict__ h, const float* __restrict__ dinv,
        const int* __restrict__ row_ptr, const int* __restrict__ col_src,
        const float* __restrict__ bias,
        unsigned short* __restrict__ ohi, int n) {
    int w = threadIdx.x >> 6, lane = threadIdx.x & 63;
    int n0 = blockIdx.x * 8 + w * 2;
    if (n0 >= n) return;
    int n1 = n0 + 1;
    bool has1 = n1 < n;
    float4 a0, a1;
    agg_two(h, row_ptr, col_src, n0, n1, has1, lane, a0, a1);

    float di0 = dinv[n0];
    float4 b = ((const float4*)bias)[lane];
    ushort4 o0;
    o0.x = (unsigned short)f2bf(fmaxf(a0.x * di0 + b.x, 0.f));
    o0.y = (unsigned short)f2bf(fmaxf(a0.y * di0 + b.y, 0.f));
    o0.z = (unsigned short)f2bf(fmaxf(a0.z * di0 + b.z, 0.f));
    o0.w = (unsigned short)f2bf(fmaxf(a0.w * di0 + b.w, 0.f));
    ((ushort4*)(ohi + (size_t)n0 * D))[lane] = o0;
    if (has1) {
        float di1 = dinv[n1];
        ushort4 o1;
        o1.x = (unsigned short)f2bf(fmaxf(a1.x * di1 + b.x, 0.f));
        o1.y = (unsigned short)f2bf(fmaxf(a1.y * di1 + b.y, 0.f));
        o1.z = (unsigned short)f2bf(fmaxf(a1.z * di1 + b.z, 0.f));
        o1.w = (unsigned short)f2bf(fmaxf(a1.w * di1 + b.w, 0.f));
        ((ushort4*)(ohi + (size_t)n1 * D))[lane] = o1;
    }
}

// layer 3: fused mean-pool accumulation (fp32, no bf16 round, no ohi write).
// Fast path (block's 8 nodes all one graph): LDS-reduce 4 waves -> 256 atomics.
__global__ __launch_bounds__(256) void k_agg3(
        const unsigned short* __restrict__ h, const float* __restrict__ dinv,
        const int* __restrict__ row_ptr, const int* __restrict__ col_src,
        const float* __restrict__ bias, const int* __restrict__ batch,
        float* __restrict__ pooled, int n) {
    __shared__ float sred[4][256];
    int w = threadIdx.x >> 6, lane = threadIdx.x & 63;
    int nb0 = blockIdx.x * 8;
    int nb1 = min(nb0 + 7, n - 1);
    bool uni = (batch[nb0] == batch[nb1]);   // block-uniform

    int n0 = nb0 + w * 2;
    int n1 = n0 + 1;
    bool act = n0 < n;
    bool has1 = n1 < n;

    float4 r0 = make_float4(0.f, 0.f, 0.f, 0.f);
    float4 r1 = make_float4(0.f, 0.f, 0.f, 0.f);
    int g0 = 0, g1 = 0;
    if (act) {
        float4 a0, a1;
        agg_two(h, row_ptr, col_src, n0, n1, has1, lane, a0, a1);
        float di0 = dinv[n0];
        float4 b = ((const float4*)bias)[lane];
        r0.x = fmaxf(a0.x * di0 + b.x, 0.f);
        r0.y = fmaxf(a0.y * di0 + b.y, 0.f);
        r0.z = fmaxf(a0.z * di0 + b.z, 0.f);
        r0.w = fmaxf(a0.w * di0 + b.w, 0.f);
        g0 = batch[n0];
        if (has1) {
            float di1 = dinv[n1];
            r1.x = fmaxf(a1.x * di1 + b.x, 0.f);
            r1.y = fmaxf(a1.y * di1 + b.y, 0.f);
            r1.z = fmaxf(a1.z * di1 + b.z, 0.f);
            r1.w = fmaxf(a1.w * di1 + b.w, 0.f);
            g1 = batch[n1];
        }
    }

    if (uni) {
        // all active nodes in this block share one graph
        float4 ws = make_float4(r0.x + r1.x, r0.y + r1.y, r0.z + r1.z, r0.w + r1.w);
        ((float4*)&sred[w][lane * 4])[0] = ws;
        __syncthreads();
        if (w == 0) {
            float4 t0 = ((const float4*)&sred[0][lane * 4])[0];
            float4 t1 = ((const float4*)&sred[1][lane * 4])[0];
            float4 t2 = ((const float4*)&sred[2][lane * 4])[0];
            float4 t3 = ((const float4*)&sred[3][lane * 4])[0];
            int g = batch[nb0];
            float* pg = pooled + g * D + lane * 4;
            atomicAdd(pg + 0, t0.x + t1.x + t2.x + t3.x);
            atomicAdd(pg + 1, t0.y + t1.y + t2.y + t3.y);
            atomicAdd(pg + 2, t0.z + t1.z + t2.z + t3.z);
            atomicAdd(pg + 3, t0.w + t1.w + t2.w + t3.w);
        }
    } else if (act) {
        // rare boundary block: per-wave atomics
        if (has1 && g1 == g0) {
            float* pg = pooled + g0 * D + lane * 4;
            atomicAdd(pg + 0, r0.x + r1.x);
            atomicAdd(pg + 1, r0.y + r1.y);
            atomicAdd(pg + 2, r0.z + r1.z);
            atomicAdd(pg + 3, r0.w + r1.w);
        } else {
            float* pg = pooled + g0 * D + lane * 4;
            atomicAdd(pg + 0, r0.x);
            atomicAdd(pg + 1, r0.y);
            atomicAdd(pg + 2, r0.z);
            atomicAdd(pg + 3, r0.w);
            if (has1) {
                float* pg1 = pooled + g1 * D + lane * 4;
                atomicAdd(pg1 + 0, r1.x);
                atomicAdd(pg1 + 1, r1.y);
                atomicAdd(pg1 + 2, r1.z);
                atomicAdd(pg1 + 3, r1.w);
            }
        }
    }
}

// ---------------- final FC ----------------

__global__ void k_fc(const float* __restrict__ pooled, const float* __restrict__ inv_cnt,
                     const float* __restrict__ W, const float* __restrict__ b,
                     float* __restrict__ out) {
    int t = blockIdx.x * blockDim.x + threadIdx.x;
    if (t >= NG * DOUT) return;
    int g = t >> 4, o = t & 15;
    float acc = 0.f;
    for (int k = 0; k < D; ++k) acc += pooled[g * D + k] * W[k * DOUT + o];
    out[t] = acc * inv_cnt[g] + b[o];
}

// ---------------- launch ----------------

extern "C" void kernel_launch(void* const* d_in, const int* in_sizes, int n_in,
                              void* d_out, int out_size, void* d_ws, size_t ws_size,
                              hipStream_t stream) {
    const float* x    = (const float*)d_in[0];
    const int*   eidx = (const int*)d_in[1];
    const int*   batch= (const int*)d_in[2];
    const float* W1   = (const float*)d_in[3];
    const float* b1   = (const float*)d_in[4];
    const float* W2   = (const float*)d_in[5];
    const float* b2   = (const float*)d_in[6];
    const float* W3   = (const float*)d_in[7];
    const float* b3   = (const float*)d_in[8];
    const float* Wfc  = (const float*)d_in[9];
    const float* bfc  = (const float*)d_in[10];
    float* out = (float*)d_out;

    const int n = in_sizes[0] / D;      // 50000
    const int E = in_sizes[1] / 2;      // 400000

    // workspace layout (256B aligned slabs)
    char* p = (char*)d_ws;
    auto take = [&](size_t bytes) -> void* {
        void* q = (void*)p;
        p += (bytes + 255) & ~(size_t)255;
        return q;
    };
    int*   cnt     = (int*)take((size_t)n * 4);
    int*   row_ptr = (int*)take((size_t)(n + 1) * 4);
    int*   cursor  = (int*)take((size_t)n * 4);
    int*   col_src = (int*)take((size_t)E * 4);
    int*   bsums   = (int*)take(256 * 4);
    float* dinv    = (float*)take((size_t)n * 4);
    float* inv_cnt = (float*)take((size_t)NG * 4);
    short* w1hi    = (short*)take((size_t)D * D * 2);
    short* w1lo    = (short*)take((size_t)D * D * 2);
    short* w2hi    = (short*)take((size_t)D * D * 2);
    short* w2lo    = (short*)take((size_t)D * D * 2);
    short* w3hi    = (short*)take((size_t)D * D * 2);
    short* w3lo    = (short*)take((size_t)D * D * 2);
    unsigned short* hbuf = (unsigned short*)take((size_t)n * D * 2);  // bf16 h'
    unsigned short* ahi  = (unsigned short*)take((size_t)n * D * 2);  // bf16 A
    float* pooled  = (float*)take((size_t)NG * D * 4);

    int tb = 256;
    int gn = (n + tb - 1) / tb;
    int ge = (E + tb - 1) / tb;
    int nb = (n + 1023) / 1024;   // 49 scan blocks
    int total4 = n * D / 4;
    int xblocks = (total4 + 255) / 256;

    k_init<<<gn, tb, 0, stream>>>(cnt, pooled, batch, inv_cnt, n);
    k_split<<<xblocks + 3 * 256, tb, 0, stream>>>(x, ahi, total4, xblocks,
                                                  W1, w1hi, w1lo, W2, w2hi, w2lo, W3, w3hi, w3lo);
    k_count<<<ge, tb, 0, stream>>>(eidx, cnt, E);
    k_scan1<<<nb, 256, 0, stream>>>(cnt, row_ptr, bsums, dinv, n);
    k_scan2<<<1, 64, 0, stream>>>(bsums, nb);
    k_scan3<<<gn, tb, 0, stream>>>(row_ptr, bsums, cursor, n, E);
    k_fill<<<ge, tb, 0, stream>>>(eidx, cursor, col_src, E);

    int ggrid = (n + 127) / 128;
    int agrid = (n + 7) / 8;

    k_gemm_mfma<<<ggrid, 256, 0, stream>>>(ahi, w1hi, w1lo, dinv, hbuf, n);
    k_agg<<<agrid, 256, 0, stream>>>(hbuf, dinv, row_ptr, col_src, b1, ahi, n);

    k_gemm_mfma<<<ggrid, 256, 0, stream>>>(ahi, w2hi, w2lo, dinv, hbuf, n);
    k_agg<<<agrid, 256, 0, stream>>>(hbuf, dinv, row_ptr, col_src, b2, ahi, n);

    k_gemm_mfma<<<ggrid, 256, 0, stream>>>(ahi, w3hi, w3lo, dinv, hbuf, n);
    k_agg3<<<agrid, 256, 0, stream>>>(hbuf, dinv, row_ptr, col_src, b3, batch, pooled, n);

    k_fc<<<4, 256, 0, stream>>>(pooled, inv_cnt, Wfc, bfc, out);
}

// Round 10
// 394.763 us; speedup vs baseline: 1.3933x; 1.0257x over previous
//
#include <hip/hip_runtime.h>

#define NN 50000
#define NE 400000
#define NG 64
#define D 256
#define DOUT 16

typedef __attribute__((ext_vector_type(8))) short bf16x8;
typedef __attribute__((ext_vector_type(4))) float f32x4;

__device__ __forceinline__ short f2bf(float x) {
    union { float f; unsigned u; } v; v.f = x;
    unsigned r = v.u + 0x7fffu + ((v.u >> 16) & 1u);   // RNE
    return (short)(r >> 16);
}
__device__ __forceinline__ float bf2f(short h) {
    union { float f; unsigned u; } v;
    v.u = ((unsigned)(unsigned short)h) << 16;
    return v.f;
}

// async global->LDS 16B copy (dest = wave-uniform base + lane*16)
__device__ __forceinline__ void async_cp16(void* lds, const void* g) {
    __builtin_amdgcn_global_load_lds(
        (const __attribute__((address_space(1))) unsigned int*)g,
        (__attribute__((address_space(3))) unsigned int*)lds, 16, 0, 0);
}

// ---------------- init: zero cnt + zero pooled + per-graph inv counts ------

__global__ void k_init(int* __restrict__ cnt, float* __restrict__ pooled,
                       const int* __restrict__ batch, float* __restrict__ inv_cnt,
                       int n) {
    int i = blockIdx.x * 256 + threadIdx.x;
    if (i < n) cnt[i] = 0;
    if (i < NG * D) pooled[i] = 0.f;
    if (blockIdx.x == 0 && threadIdx.x < NG) {
        int g = threadIdx.x;
        int lo = 0, hi = n;
        while (lo < hi) { int mid = (lo + hi) >> 1; if (batch[mid] < g) lo = mid + 1; else hi = mid; }
        int start = lo;
        hi = n;
        while (lo < hi) { int mid = (lo + hi) >> 1; if (batch[mid] < g + 1) lo = mid + 1; else hi = mid; }
        inv_cnt[g] = 1.f / fmaxf((float)(lo - start), 1.f);
    }
}

__global__ void k_count(const int* __restrict__ eidx, int* __restrict__ cnt, int E) {
    int e = blockIdx.x * blockDim.x + threadIdx.x;
    if (e < E) atomicAdd(&cnt[eidx[E + e]], 1);
}

// exclusive scan of cnt[n] -> row_ptr[n] (+ dinv from final counts), 1024 elems/block
__global__ void k_scan1(const int* __restrict__ cnt, int* __restrict__ excl,
                        int* __restrict__ bsums, float* __restrict__ dinv, int n) {
    __shared__ int sh[256];
    int tid = threadIdx.x;
    int base = blockIdx.x * 1024;
    int v[4]; int tsum = 0;
    for (int j = 0; j < 4; ++j) {
        int i = base + tid * 4 + j;
        v[j] = (i < n) ? cnt[i] : 0;
        if (i < n) dinv[i] = rsqrtf((float)(v[j] + 1));  // +1 self-loop
        tsum += v[j];
    }
    sh[tid] = tsum; __syncthreads();
    for (int d = 1; d < 256; d <<= 1) {
        int t = (tid >= d) ? sh[tid - d] : 0;
        __syncthreads();
        sh[tid] += t;
        __syncthreads();
    }
    int run = sh[tid] - tsum;  // exclusive offset within block
    for (int j = 0; j < 4; ++j) {
        int i = base + tid * 4 + j;
        if (i < n) excl[i] = run;
        run += v[j];
    }
    if (tid == 255) bsums[blockIdx.x] = sh[255];
}

__global__ void k_scan2(int* bsums, int nb) {
    __shared__ int sh[64];
    int tid = threadIdx.x;
    int v = (tid < nb) ? bsums[tid] : 0;
    sh[tid] = v; __syncthreads();
    for (int d = 1; d < 64; d <<= 1) {
        int t = (tid >= d) ? sh[tid - d] : 0;
        __syncthreads();
        sh[tid] += t;
        __syncthreads();
    }
    if (tid < nb) bsums[tid] = sh[tid] - v;  // exclusive
}

__global__ void k_scan3(int* __restrict__ row_ptr, const int* __restrict__ bsums,
                        int* __restrict__ cursor, int n, int E) {
    int i = blockIdx.x * blockDim.x + threadIdx.x;
    if (i < n) {
        int v = row_ptr[i] + bsums[i >> 10];
        row_ptr[i] = v;
        cursor[i] = v;
    }
    if (i == 0) row_ptr[n] = E;
}

__global__ void k_fill(const int* __restrict__ eidx, int* __restrict__ cursor,
                       int* __restrict__ col_src, int E) {
    int e = blockIdx.x * blockDim.x + threadIdx.x;
    if (e < E) {
        int d = eidx[E + e];
        int pos = atomicAdd(&cursor[d], 1);
        col_src[pos] = eidx[e];
    }
}

// ---------------- split: x -> bf16 (hi only) + 3x W -> W^T hi/lo ----------

__global__ void k_split(const float* __restrict__ x, unsigned short* __restrict__ ahi,
                        int total4, int xblocks,
                        const float* __restrict__ W1, short* __restrict__ w1hi, short* __restrict__ w1lo,
                        const float* __restrict__ W2, short* __restrict__ w2hi, short* __restrict__ w2lo,
                        const float* __restrict__ W3, short* __restrict__ w3hi, short* __restrict__ w3lo) {
    if (blockIdx.x < (unsigned)xblocks) {
        int i = blockIdx.x * 256 + threadIdx.x;
        if (i >= total4) return;
        float4 v = ((const float4*)x)[i];
        ushort4 h;
        h.x = (unsigned short)f2bf(v.x);
        h.y = (unsigned short)f2bf(v.y);
        h.z = (unsigned short)f2bf(v.z);
        h.w = (unsigned short)f2bf(v.w);
        ((ushort4*)ahi)[i] = h;
    } else {
        int wb = blockIdx.x - xblocks;
        int which = wb >> 8;               // 0..2
        int idx = (wb & 255) * 256 + threadIdx.x;   // idx = n*256 + k
        int nn = idx >> 8, k = idx & 255;
        const float* W = (which == 0) ? W1 : (which == 1) ? W2 : W3;
        short* Whi = (which == 0) ? w1hi : (which == 1) ? w2hi : w3hi;
        short* Wlo = (which == 0) ? w1lo : (which == 1) ? w2lo : w3lo;
        float xv = W[k * 256 + nn];
        short h = f2bf(xv);
        Whi[idx] = h;
        Wlo[idx] = f2bf(xv - bf2f(h));
    }
}

// ---------------- MFMA GEMM: 128x256 tile, LDS-staged via global_load_lds --
// A bf16 [M][256] (hi only); Wt hi/lo bf16 [256 n][256 k]. 4 waves of 64x128,
// BK=32, full N in one block (A fetched ONCE). XOR swizzle q = c ^ ((r>>1)&3)
// folded into global source address. A*B ~= Ah*Bh + Ah*Bl.

__global__ __launch_bounds__(256, 2) void k_gemm_mfma(
        const unsigned short* __restrict__ A,
        const short* __restrict__ Whi, const short* __restrict__ Wlo,
        const float* __restrict__ dinv, unsigned short* __restrict__ C, int M) {
    __shared__ short Ah_s[4096];   //  8 KB: 128 rows x 32 k, swizzled
    __shared__ short Bh_s[8192];   // 16 KB: 256 rows x 32 k
    __shared__ short Bl_s[8192];   // 16 KB

    const int tid = threadIdx.x;
    const int bm = blockIdx.x * 128;

    const int lane = tid & 63;
    const int w    = tid >> 6;
    const int wm   = w & 1;        // wave row half (0-1): 64 rows
    const int wn   = w >> 1;       // wave col half (0-1): 128 cols
    const int lm   = lane & 15;
    const int quad = lane >> 4;

    // staging source addressing: per issue of 64 rows, thread covers row tid>>2,
    // 16B chunk c = tid&3, holding swizzled quad q = c ^ ((srow>>1)&3)
    const int srow = tid >> 2, c = tid & 3;
    const int q = c ^ ((srow >> 1) & 3);          // j*64 doesn't affect (row>>1)&3
    int ga0 = bm + srow;        if (ga0 >= M) ga0 = M - 1;
    int ga1 = bm + 64 + srow;   if (ga1 >= M) ga1 = M - 1;
    const unsigned short* pa0 = A + ((size_t)ga0 << 8) + q * 8;
    const unsigned short* pa1 = A + ((size_t)ga1 << 8) + q * 8;
    const short* pbh[4]; const short* pbl[4];
    #pragma unroll
    for (int j = 0; j < 4; ++j) {
        pbh[j] = Whi + ((size_t)(j * 64 + srow) << 8) + q * 8;
        pbl[j] = Wlo + ((size_t)(j * 64 + srow) << 8) + q * 8;
    }

    const int stA0 = w * 512, stA1 = 2048 + w * 512;   // shorts
    int stB[4];
    #pragma unroll
    for (int j = 0; j < 4; ++j) stB[j] = j * 2048 + w * 512;

    // fragment LDS offsets (k0-invariant)
    int oa[4], ob[8];
    #pragma unroll
    for (int i = 0; i < 4; ++i) {
        int ra = wm * 64 + i * 16 + lm;
        oa[i] = ra * 32 + ((quad ^ ((ra >> 1) & 3)) * 8);
    }
    #pragma unroll
    for (int i = 0; i < 8; ++i) {
        int rb = wn * 128 + i * 16 + lm;
        ob[i] = rb * 32 + ((quad ^ ((rb >> 1) & 3)) * 8);
    }

    f32x4 acc[4][8];
    #pragma unroll
    for (int i = 0; i < 4; ++i)
        #pragma unroll
        for (int j = 0; j < 8; ++j)
            acc[i][j] = (f32x4){0.f, 0.f, 0.f, 0.f};

    for (int k0 = 0; k0 < D; k0 += 32) {
        async_cp16(&Ah_s[stA0], pa0 + k0);
        async_cp16(&Ah_s[stA1], pa1 + k0);
        #pragma unroll
        for (int j = 0; j < 4; ++j) {
            async_cp16(&Bh_s[stB[j]], pbh[j] + k0);
            async_cp16(&Bl_s[stB[j]], pbl[j] + k0);
        }
        __syncthreads();

        bf16x8 Ah[4], Bh[8], Bl[8];
        #pragma unroll
        for (int i = 0; i < 4; ++i) Ah[i] = *(const bf16x8*)&Ah_s[oa[i]];
        #pragma unroll
        for (int i = 0; i < 8; ++i) {
            Bh[i] = *(const bf16x8*)&Bh_s[ob[i]];
            Bl[i] = *(const bf16x8*)&Bl_s[ob[i]];
        }
        #pragma unroll
        for (int mi = 0; mi < 4; ++mi)
            #pragma unroll
            for (int ni = 0; ni < 8; ++ni) {
                acc[mi][ni] = __builtin_amdgcn_mfma_f32_16x16x32_bf16(Ah[mi], Bh[ni], acc[mi][ni], 0, 0, 0);
                acc[mi][ni] = __builtin_amdgcn_mfma_f32_16x16x32_bf16(Ah[mi], Bl[ni], acc[mi][ni], 0, 0, 0);
            }
        __syncthreads();
    }

    // epilogue: C[row][col] = bf16(acc * dinv[row])
    #pragma unroll
    for (int mi = 0; mi < 4; ++mi) {
        int rbase = bm + wm * 64 + mi * 16 + quad * 4;
        #pragma unroll
        for (int r = 0; r < 4; ++r) {
            int grow = rbase + r;
            if (grow < M) {
                float s = dinv[grow];
                #pragma unroll
                for (int ni = 0; ni < 8; ++ni) {
                    int col = wn * 128 + ni * 16 + lm;
                    C[(size_t)grow * D + col] = (unsigned short)f2bf(acc[mi][ni][r] * s);
                }
            }
        }
    }
}

// ---------------- agg core: accumulate h'[node] + sum h'[src] (2 nodes/wave) --

__device__ __forceinline__ void agg_two(
        const unsigned short* __restrict__ h, const int* __restrict__ row_ptr,
        const int* __restrict__ col_src, int n0, int n1, bool has1, int lane,
        float4& a0, float4& a1) {
    ushort4 s0 = ((const ushort4*)(h + (size_t)n0 * D))[lane];
    a0 = make_float4(bf2f(s0.x), bf2f(s0.y), bf2f(s0.z), bf2f(s0.w));
    a1 = make_float4(0.f, 0.f, 0.f, 0.f);
    if (has1) {
        ushort4 s1 = ((const ushort4*)(h + (size_t)n1 * D))[lane];
        a1 = make_float4(bf2f(s1.x), bf2f(s1.y), bf2f(s1.z), bf2f(s1.w));
    }
    int c0 = row_ptr[n0], e0 = row_ptr[n0 + 1];
    int c1 = e0, e1 = has1 ? row_ptr[n1 + 1] : e0;   // CSR-contiguous

    while (c0 < e0 || c1 < e1) {
        int cnt0 = min(64, e0 - c0); if (cnt0 < 0) cnt0 = 0;
        int cnt1 = min(64, e1 - c1); if (cnt1 < 0) cnt1 = 0;
        int i0 = (lane < cnt0) ? col_src[c0 + lane] : 0;
        int i1 = (lane < cnt1) ? col_src[c1 + lane] : 0;
        int m = max(cnt0, cnt1);
        for (int e = 0; e < m; e += 8) {
            int k0 = cnt0 - e;                        // wave-uniform
            int k1 = cnt1 - e;
            ushort4 u0[8], u1[8];
            #pragma unroll
            for (int j = 0; j < 8; ++j)
                if (j < k0) {
                    int s = __shfl(i0, e + j);
                    u0[j] = ((const ushort4*)(h + (size_t)s * D))[lane];
                }
            #pragma unroll
            for (int j = 0; j < 8; ++j)
                if (j < k1) {
                    int s = __shfl(i1, e + j);
                    u1[j] = ((const ushort4*)(h + (size_t)s * D))[lane];
                }
            #pragma unroll
            for (int j = 0; j < 8; ++j)
                if (j < k0) {
                    a0.x += bf2f(u0[j].x); a0.y += bf2f(u0[j].y);
                    a0.z += bf2f(u0[j].z); a0.w += bf2f(u0[j].w);
                }
            #pragma unroll
            for (int j = 0; j < 8; ++j)
                if (j < k1) {
                    a1.x += bf2f(u1[j].x); a1.y += bf2f(u1[j].y);
                    a1.z += bf2f(u1[j].z); a1.w += bf2f(u1[j].w);
                }
        }
        c0 += cnt0; c1 += cnt1;
    }
}

// all layers: out = relu(dinv*(acc) + b) written bf16 (next GEMM's A / pool src)
__global__ __launch_bounds__(256) void k_agg(
        const unsigned short* __restrict__ h, const float* __restrict__ dinv,
        const int* __restrict__ row_ptr, const int* __restrict__ col_src,
        const float* __restrict__ bias,
        unsigned short* __restrict__ ohi, int n) {
    int w = threadIdx.x >> 6, lane = threadIdx.x & 63;
    int n0 = blockIdx.x * 8 + w * 2;
    if (n0 >= n) return;
    int n1 = n0 + 1;
    bool has1 = n1 < n;
    float4 a0, a1;
    agg_two(h, row_ptr, col_src, n0, n1, has1, lane, a0, a1);

    float di0 = dinv[n0];
    float4 b = ((const float4*)bias)[lane];
    ushort4 o0;
    o0.x = (unsigned short)f2bf(fmaxf(a0.x * di0 + b.x, 0.f));
    o0.y = (unsigned short)f2bf(fmaxf(a0.y * di0 + b.y, 0.f));
    o0.z = (unsigned short)f2bf(fmaxf(a0.z * di0 + b.z, 0.f));
    o0.w = (unsigned short)f2bf(fmaxf(a0.w * di0 + b.w, 0.f));
    ((ushort4*)(ohi + (size_t)n0 * D))[lane] = o0;
    if (has1) {
        float di1 = dinv[n1];
        ushort4 o1;
        o1.x = (unsigned short)f2bf(fmaxf(a1.x * di1 + b.x, 0.f));
        o1.y = (unsigned short)f2bf(fmaxf(a1.y * di1 + b.y, 0.f));
        o1.z = (unsigned short)f2bf(fmaxf(a1.z * di1 + b.z, 0.f));
        o1.w = (unsigned short)f2bf(fmaxf(a1.w * di1 + b.w, 0.f));
        ((ushort4*)(ohi + (size_t)n1 * D))[lane] = o1;
    }
}

// ---------------- mean pool, stage 1: chunked sums + atomic flush ----------
// 64 contiguous nodes/block, register accumulate, atomics only at graph edges.

__global__ __launch_bounds__(256) void k_pool_sum(
        const unsigned short* __restrict__ hi,
        const int* __restrict__ batch, float* __restrict__ pooled, int n) {
    int beg = blockIdx.x * 64;
    if (beg >= n) return;
    int end = min(beg + 64, n);
    int t = threadIdx.x;  // dim t
    float acc = 0.f;
    int cur = batch[beg];
    for (int i = beg; i < end; ++i) {
        int g = batch[i];
        if (g != cur) {
            atomicAdd(&pooled[cur * D + t], acc);
            acc = 0.f;
            cur = g;
        }
        acc += bf2f(hi[(size_t)i * D + t]);
    }
    atomicAdd(&pooled[cur * D + t], acc);
}

// ---------------- final FC ----------------

__global__ void k_fc(const float* __restrict__ pooled, const float* __restrict__ inv_cnt,
                     const float* __restrict__ W, const float* __restrict__ b,
                     float* __restrict__ out) {
    int t = blockIdx.x * blockDim.x + threadIdx.x;
    if (t >= NG * DOUT) return;
    int g = t >> 4, o = t & 15;
    float acc = 0.f;
    for (int k = 0; k < D; ++k) acc += pooled[g * D + k] * W[k * DOUT + o];
    out[t] = acc * inv_cnt[g] + b[o];
}

// ---------------- launch ----------------

extern "C" void kernel_launch(void* const* d_in, const int* in_sizes, int n_in,
                              void* d_out, int out_size, void* d_ws, size_t ws_size,
                              hipStream_t stream) {
    const float* x    = (const float*)d_in[0];
    const int*   eidx = (const int*)d_in[1];
    const int*   batch= (const int*)d_in[2];
    const float* W1   = (const float*)d_in[3];
    const float* b1   = (const float*)d_in[4];
    const float* W2   = (const float*)d_in[5];
    const float* b2   = (const float*)d_in[6];
    const float* W3   = (const float*)d_in[7];
    const float* b3   = (const float*)d_in[8];
    const float* Wfc  = (const float*)d_in[9];
    const float* bfc  = (const float*)d_in[10];
    float* out = (float*)d_out;

    const int n = in_sizes[0] / D;      // 50000
    const int E = in_sizes[1] / 2;      // 400000

    // workspace layout (256B aligned slabs)
    char* p = (char*)d_ws;
    auto take = [&](size_t bytes) -> void* {
        void* q = (void*)p;
        p += (bytes + 255) & ~(size_t)255;
        return q;
    };
    int*   cnt     = (int*)take((size_t)n * 4);
    int*   row_ptr = (int*)take((size_t)(n + 1) * 4);
    int*   cursor  = (int*)take((size_t)n * 4);
    int*   col_src = (int*)take((size_t)E * 4);
    int*   bsums   = (int*)take(256 * 4);
    float* dinv    = (float*)take((size_t)n * 4);
    float* inv_cnt = (float*)take((size_t)NG * 4);
    short* w1hi    = (short*)take((size_t)D * D * 2);
    short* w1lo    = (short*)take((size_t)D * D * 2);
    short* w2hi    = (short*)take((size_t)D * D * 2);
    short* w2lo    = (short*)take((size_t)D * D * 2);
    short* w3hi    = (short*)take((size_t)D * D * 2);
    short* w3lo    = (short*)take((size_t)D * D * 2);
    unsigned short* hbuf = (unsigned short*)take((size_t)n * D * 2);  // bf16 h'
    unsigned short* ahi  = (unsigned short*)take((size_t)n * D * 2);  // bf16 A
    float* pooled  = (float*)take((size_t)NG * D * 4);

    int tb = 256;
    int gn = (n + tb - 1) / tb;
    int ge = (E + tb - 1) / tb;
    int nb = (n + 1023) / 1024;   // 49 scan blocks
    int total4 = n * D / 4;
    int xblocks = (total4 + 255) / 256;

    k_init<<<gn, tb, 0, stream>>>(cnt, pooled, batch, inv_cnt, n);
    k_split<<<xblocks + 3 * 256, tb, 0, stream>>>(x, ahi, total4, xblocks,
                                                  W1, w1hi, w1lo, W2, w2hi, w2lo, W3, w3hi, w3lo);
    k_count<<<ge, tb, 0, stream>>>(eidx, cnt, E);
    k_scan1<<<nb, 256, 0, stream>>>(cnt, row_ptr, bsums, dinv, n);
    k_scan2<<<1, 64, 0, stream>>>(bsums, nb);
    k_scan3<<<gn, tb, 0, stream>>>(row_ptr, bsums, cursor, n, E);
    k_fill<<<ge, tb, 0, stream>>>(eidx, cursor, col_src, E);

    int ggrid = (n + 127) / 128;
    int agrid = (n + 7) / 8;

    k_gemm_mfma<<<ggrid, 256, 0, stream>>>(ahi, w1hi, w1lo, dinv, hbuf, n);
    k_agg<<<agrid, 256, 0, stream>>>(hbuf, dinv, row_ptr, col_src, b1, ahi, n);

    k_gemm_mfma<<<ggrid, 256, 0, stream>>>(ahi, w2hi, w2lo, dinv, hbuf, n);
    k_agg<<<agrid, 256, 0, stream>>>(hbuf, dinv, row_ptr, col_src, b2, ahi, n);

    k_gemm_mfma<<<ggrid, 256, 0, stream>>>(ahi, w3hi, w3lo, dinv, hbuf, n);
    k_agg<<<agrid, 256, 0, stream>>>(hbuf, dinv, row_ptr, col_src, b3, ahi, n);

    k_pool_sum<<<(n + 63) / 64, 256, 0, stream>>>(ahi, batch, pooled, n);
    k_fc<<<4, 256, 0, stream>>>(pooled, inv_cnt, Wfc, bfc, out);
}